// Round 10
// baseline (251.227 us; speedup 1.0000x reference)
//
#include <hip/hip_runtime.h>
#include <hip/hip_fp16.h>
#include <math.h>

#define NB 8
#define NS 2048
#define NN (NB*NS)       // 16384 nodes
#define NE (NN*16)       // 262144 edges
#define EPSF 1e-5f

typedef float  f32x4 __attribute__((ext_vector_type(4)));
typedef _Float16 f16x8 __attribute__((ext_vector_type(8)));
union F8 { f16x8 v; unsigned u[4]; };

__device__ __forceinline__ unsigned pk2h(float a, float b) {
    __half2 hh = __floats2half2_rn(a, b);
    unsigned u; __builtin_memcpy(&u, &hh, 4); return u;
}

// zero deg (NN) and acc (4)
__global__ __launch_bounds__(256) void k_init(int* __restrict__ deg,
                                              float* __restrict__ acc)
{
    int i = blockIdx.x*256 + threadIdx.x;
    if (i < NN) deg[i] = 0;
    if (i < 4) acc[i] = 0.f;
}

// Layer 0 (MFMA): slotted-CSR scatter; enc -> h; A = h@W1a+b1; Bm = h@W1b; zero g0.
__global__ __launch_bounds__(256) void k_pre0M(
    const float* __restrict__ x,
    const float* __restrict__ encW, const float* __restrict__ encB,
    float* __restrict__ h,
    const float* __restrict__ W1, const float* __restrict__ B1,
    float* __restrict__ A, float* __restrict__ Bm,
    float* __restrict__ gz,
    const int* __restrict__ srcv, const int* __restrict__ tgtv,
    int* __restrict__ deg, int* __restrict__ ssrc)
{
    alignas(16) __shared__ _Float16 sWp[8192];   // [ks2][nt8][qd4][col16][j8]
    __shared__ float sEw[256], sEb[64];
    {   // slotted-CSR scatter: 4 edges per thread (256 blocks x 256 thr)
        int gid = blockIdx.x*256 + threadIdx.x;
        #pragma unroll
        for (int it = 0; it < 4; it++) {
            int e = gid + it*65536;
            int t = tgtv[e];
            int pos = atomicAdd(&deg[t], 1) & 63;
            ssrc[t*64 + pos] = srcv[e];
        }
    }
    for (int idx = threadIdx.x; idx < 8192; idx += 256) {
        int k = idx >> 7, n = idx & 127;
        float val = (n < 64) ? W1[k*64 + n] : W1[(64+k)*64 + (n-64)];
        int ks = k >> 5, qd = (k >> 3) & 3, j = k & 7, nt = n >> 4, cl = n & 15;
        sWp[(((ks*8+nt)*4+qd)*16+cl)*8 + j] = (_Float16)val;
    }
    sEw[threadIdx.x] = encW[threadIdx.x];
    if (threadIdx.x < 64) sEb[threadIdx.x] = encB[threadIdx.x];
    if (blockIdx.x == 0)
        for (int i = threadIdx.x; i < 2*NB*64; i += 256) gz[i] = 0.f;
    __syncthreads();
    const int lane = threadIdx.x & 63;
    const int wv = threadIdx.x >> 6;
    const int col = lane & 15, quad = lane >> 4;
    const int n0w = blockIdx.x*64 + wv*16;
    const int n = n0w + col;
    float4 x4 = *(const float4*)&x[(size_t)n*4];
    float xv[16];
    #pragma unroll
    for (int hh = 0; hh < 2; hh++)
        #pragma unroll
        for (int j = 0; j < 8; j++) {
            int f = hh*32 + quad*8 + j;
            float v = sEb[f];
            v = fmaf(x4.x, sEw[f],     v);
            v = fmaf(x4.y, sEw[64+f],  v);
            v = fmaf(x4.z, sEw[128+f], v);
            v = fmaf(x4.w, sEw[192+f], v);
            xv[hh*8+j] = v;
        }
    float* hp = &h[(size_t)n*64 + quad*8];
    *(float4*)&hp[0]  = *(float4*)&xv[0];
    *(float4*)&hp[4]  = *(float4*)&xv[4];
    *(float4*)&hp[32] = *(float4*)&xv[8];
    *(float4*)&hp[36] = *(float4*)&xv[12];
    F8 af0, af1;
    af0.u[0] = pk2h(xv[0],  xv[1]);  af0.u[1] = pk2h(xv[2],  xv[3]);
    af0.u[2] = pk2h(xv[4],  xv[5]);  af0.u[3] = pk2h(xv[6],  xv[7]);
    af1.u[0] = pk2h(xv[8],  xv[9]);  af1.u[1] = pk2h(xv[10], xv[11]);
    af1.u[2] = pk2h(xv[12], xv[13]); af1.u[3] = pk2h(xv[14], xv[15]);
    float b1v[4];
    #pragma unroll
    for (int nt = 0; nt < 4; nt++) b1v[nt] = B1[nt*16+col];
    #pragma unroll
    for (int nt = 0; nt < 8; nt++) {
        f32x4 acc = {0.f,0.f,0.f,0.f};
        F8 bf; bf.v = *(const f16x8*)&sWp[(((0*8+nt)*4+quad)*16+col)*8];
        acc = __builtin_amdgcn_mfma_f32_16x16x32_f16(af0.v, bf.v, acc, 0, 0, 0);
        bf.v = *(const f16x8*)&sWp[(((1*8+nt)*4+quad)*16+col)*8];
        acc = __builtin_amdgcn_mfma_f32_16x16x32_f16(af1.v, bf.v, acc, 0, 0, 0);
        if (nt < 4) {
            float bb = b1v[nt];
            A[(size_t)(n0w + quad*4 + 0)*64 + nt*16 + col] = acc.x + bb;
            A[(size_t)(n0w + quad*4 + 1)*64 + nt*16 + col] = acc.y + bb;
            A[(size_t)(n0w + quad*4 + 2)*64 + nt*16 + col] = acc.z + bb;
            A[(size_t)(n0w + quad*4 + 3)*64 + nt*16 + col] = acc.w + bb;
        } else {
            Bm[(size_t)(n0w + quad*4 + 0)*64 + (nt-4)*16 + col] = acc.x;
            Bm[(size_t)(n0w + quad*4 + 1)*64 + (nt-4)*16 + col] = acc.y;
            Bm[(size_t)(n0w + quad*4 + 2)*64 + (nt-4)*16 + col] = acc.z;
            Bm[(size_t)(n0w + quad*4 + 3)*64 + (nt-4)*16 + col] = acc.w;
        }
    }
}

// Fused edge+update; edge phase pair-interleaves 2 targets for 2x memory-level
// parallelism (both targets' gathers issued before either MFMA pack).
__global__ __launch_bounds__(256, 3) void k_eu(
    const float* __restrict__ A, const float* __restrict__ Bm,
    const int* __restrict__ deg, const int* __restrict__ ssrc,
    const float* __restrict__ W2e, const float* __restrict__ B2e,
    float* __restrict__ h,
    const float* __restrict__ W1u, const float* __restrict__ B1u,
    const float* __restrict__ W2u, const float* __restrict__ B2u,
    float* __restrict__ gout)
{
    alignas(16) __shared__ _Float16 sW1u[8192];   // u1 packed
    alignas(16) __shared__ _Float16 sW2u[4096];   // u2 packed
    alignas(16) __shared__ _Float16 sM2[4096];    // m2 packed (edge W2)
    alignas(16) __shared__ float sAgg[16*68];     // agg tile, reused as hid tile
    for (int idx = threadIdx.x; idx < 8192; idx += 256) {
        int k = idx >> 6, n = idx & 63;
        int ks = k >> 5, qd = (k >> 3) & 3, j = k & 7, nt = n >> 4, cl = n & 15;
        sW1u[(((ks*4+nt)*4+qd)*16+cl)*8 + j] = (_Float16)W1u[idx];
    }
    for (int idx = threadIdx.x; idx < 4096; idx += 256) {
        int k = idx >> 6, n = idx & 63;
        int ks = k >> 5, qd = (k >> 3) & 3, j = k & 7, nt = n >> 4, cl = n & 15;
        sW2u[(((ks*4+nt)*4+qd)*16+cl)*8 + j] = (_Float16)W2u[idx];
        sM2 [(((ks*4+nt)*4+qd)*16+cl)*8 + j] = (_Float16)W2e[idx];
    }
    __syncthreads();
    const int lane = threadIdx.x & 63;
    const int wv = threadIdx.x >> 6;
    const int col = lane & 15, quad = lane >> 4;
    F8 bfe[4][2];
    #pragma unroll
    for (int nt = 0; nt < 4; nt++)
        #pragma unroll
        for (int ks = 0; ks < 2; ks++)
            bfe[nt][ks].v = *(const f16x8*)&sM2[(((ks*4+nt)*4+quad)*16+col)*8];
    float b2e[4];
    #pragma unroll
    for (int nt = 0; nt < 4; nt++) b2e[nt] = B2e[nt*16 + col];

    const int t_base = blockIdx.x * 16;
    int cnts[4], sv[4];
    #pragma unroll
    for (int m = 0; m < 4; m++) {
        int t = t_base + wv*4 + m;
        int c = deg[t];
        cnts[m] = c > 64 ? 64 : c;
        sv[m] = ssrc[t*64 + lane];
    }
    #pragma unroll
    for (int mp = 0; mp < 2; mp++) {
        const int mA = mp*2, mB = mp*2 + 1;
        const int tA = t_base + wv*4 + mA;
        const int tB = t_base + wv*4 + mB;
        const float* arA = &A[(size_t)tA*64 + quad*8];
        const float* arB = &A[(size_t)tB*64 + quad*8];
        float4 aA0 = *(const float4*)&arA[0];
        float4 aA1 = *(const float4*)&arA[4];
        float4 aA2 = *(const float4*)&arA[32];
        float4 aA3 = *(const float4*)&arA[36];
        float4 aB0 = *(const float4*)&arB[0];
        float4 aB1 = *(const float4*)&arB[4];
        float4 aB2 = *(const float4*)&arB[32];
        float4 aB3 = *(const float4*)&arB[36];
        float csA[4] = {0.f,0.f,0.f,0.f};
        float csB[4] = {0.f,0.f,0.f,0.f};
        const int cA = cnts[mA], cB = cnts[mB];
        const int cmax = cA > cB ? cA : cB;
        for (int s0 = 0; s0 < cmax; s0 += 16) {
            const int vA = cA - s0, vB = cB - s0;   // wave-uniform
            float4 bA0, bA1, bA2, bA3, bB0, bB1, bB2, bB3;
            if (vA > 0) {   // issue target-A gather
                int cc = col < vA-1 ? col : vA-1;
                int sr = __shfl(sv[mA], s0 + cc, 64);
                const float* br = &Bm[(size_t)sr*64 + quad*8];
                bA0 = *(const float4*)&br[0];
                bA1 = *(const float4*)&br[4];
                bA2 = *(const float4*)&br[32];
                bA3 = *(const float4*)&br[36];
            }
            if (vB > 0) {   // issue target-B gather (overlaps A's latency)
                int cc = col < vB-1 ? col : vB-1;
                int sr = __shfl(sv[mB], s0 + cc, 64);
                const float* br = &Bm[(size_t)sr*64 + quad*8];
                bB0 = *(const float4*)&br[0];
                bB1 = *(const float4*)&br[4];
                bB2 = *(const float4*)&br[32];
                bB3 = *(const float4*)&br[36];
            }
            if (vA > 0) {
                F8 af0, af1;
                af0.u[0] = pk2h(fmaxf(aA0.x+bA0.x,0.f), fmaxf(aA0.y+bA0.y,0.f));
                af0.u[1] = pk2h(fmaxf(aA0.z+bA0.z,0.f), fmaxf(aA0.w+bA0.w,0.f));
                af0.u[2] = pk2h(fmaxf(aA1.x+bA1.x,0.f), fmaxf(aA1.y+bA1.y,0.f));
                af0.u[3] = pk2h(fmaxf(aA1.z+bA1.z,0.f), fmaxf(aA1.w+bA1.w,0.f));
                af1.u[0] = pk2h(fmaxf(aA2.x+bA2.x,0.f), fmaxf(aA2.y+bA2.y,0.f));
                af1.u[1] = pk2h(fmaxf(aA2.z+bA2.z,0.f), fmaxf(aA2.w+bA2.w,0.f));
                af1.u[2] = pk2h(fmaxf(aA3.x+bA3.x,0.f), fmaxf(aA3.y+bA3.y,0.f));
                af1.u[3] = pk2h(fmaxf(aA3.z+bA3.z,0.f), fmaxf(aA3.w+bA3.w,0.f));
                #pragma unroll
                for (int nt = 0; nt < 4; nt++) {
                    f32x4 acc = __builtin_amdgcn_mfma_f32_16x16x32_f16(
                                    af0.v, bfe[nt][0].v, (f32x4){0.f,0.f,0.f,0.f}, 0, 0, 0);
                    acc = __builtin_amdgcn_mfma_f32_16x16x32_f16(
                                    af1.v, bfe[nt][1].v, acc, 0, 0, 0);
                    float r0 = (quad*4+0 < vA) ? fmaxf(acc.x + b2e[nt], 0.f) : 0.f;
                    float r1 = (quad*4+1 < vA) ? fmaxf(acc.y + b2e[nt], 0.f) : 0.f;
                    float r2 = (quad*4+2 < vA) ? fmaxf(acc.z + b2e[nt], 0.f) : 0.f;
                    float r3 = (quad*4+3 < vA) ? fmaxf(acc.w + b2e[nt], 0.f) : 0.f;
                    csA[nt] += (r0 + r1) + (r2 + r3);
                }
            }
            if (vB > 0) {
                F8 af0, af1;
                af0.u[0] = pk2h(fmaxf(aB0.x+bB0.x,0.f), fmaxf(aB0.y+bB0.y,0.f));
                af0.u[1] = pk2h(fmaxf(aB0.z+bB0.z,0.f), fmaxf(aB0.w+bB0.w,0.f));
                af0.u[2] = pk2h(fmaxf(aB1.x+bB1.x,0.f), fmaxf(aB1.y+bB1.y,0.f));
                af0.u[3] = pk2h(fmaxf(aB1.z+bB1.z,0.f), fmaxf(aB1.w+bB1.w,0.f));
                af1.u[0] = pk2h(fmaxf(aB2.x+bB2.x,0.f), fmaxf(aB2.y+bB2.y,0.f));
                af1.u[1] = pk2h(fmaxf(aB2.z+bB2.z,0.f), fmaxf(aB2.w+bB2.w,0.f));
                af1.u[2] = pk2h(fmaxf(aB3.x+bB3.x,0.f), fmaxf(aB3.y+bB3.y,0.f));
                af1.u[3] = pk2h(fmaxf(aB3.z+bB3.z,0.f), fmaxf(aB3.w+bB3.w,0.f));
                #pragma unroll
                for (int nt = 0; nt < 4; nt++) {
                    f32x4 acc = __builtin_amdgcn_mfma_f32_16x16x32_f16(
                                    af0.v, bfe[nt][0].v, (f32x4){0.f,0.f,0.f,0.f}, 0, 0, 0);
                    acc = __builtin_amdgcn_mfma_f32_16x16x32_f16(
                                    af1.v, bfe[nt][1].v, acc, 0, 0, 0);
                    float r0 = (quad*4+0 < vB) ? fmaxf(acc.x + b2e[nt], 0.f) : 0.f;
                    float r1 = (quad*4+1 < vB) ? fmaxf(acc.y + b2e[nt], 0.f) : 0.f;
                    float r2 = (quad*4+2 < vB) ? fmaxf(acc.z + b2e[nt], 0.f) : 0.f;
                    float r3 = (quad*4+3 < vB) ? fmaxf(acc.w + b2e[nt], 0.f) : 0.f;
                    csB[nt] += (r0 + r1) + (r2 + r3);
                }
            }
        }
        #pragma unroll
        for (int nt = 0; nt < 4; nt++) {
            float vv = csA[nt];
            vv += __shfl_down(vv, 32, 64);
            vv += __shfl_down(vv, 16, 64);
            csA[nt] = vv;
            float ww = csB[nt];
            ww += __shfl_down(ww, 32, 64);
            ww += __shfl_down(ww, 16, 64);
            csB[nt] = ww;
        }
        if (lane < 16) {
            sAgg[(wv*4+mA)*68 +  0 + lane] = csA[0];
            sAgg[(wv*4+mA)*68 + 16 + lane] = csA[1];
            sAgg[(wv*4+mA)*68 + 32 + lane] = csA[2];
            sAgg[(wv*4+mA)*68 + 48 + lane] = csA[3];
            sAgg[(wv*4+mB)*68 +  0 + lane] = csB[0];
            sAgg[(wv*4+mB)*68 + 16 + lane] = csB[1];
            sAgg[(wv*4+mB)*68 + 32 + lane] = csB[2];
            sAgg[(wv*4+mB)*68 + 48 + lane] = csB[3];
        }
    }
    __syncthreads();
    if (wv == 0) {
        const int n0w = t_base;
        const float* hp = &h[(size_t)(n0w+col)*64 + quad*8];
        float4 h0 = *(const float4*)&hp[0];
        float4 h1 = *(const float4*)&hp[4];
        float4 h2 = *(const float4*)&hp[32];
        float4 h3 = *(const float4*)&hp[36];
        const float* ap = &sAgg[col*68 + quad*8];
        float4 g0 = *(const float4*)&ap[0];
        float4 g1 = *(const float4*)&ap[4];
        float4 g2 = *(const float4*)&ap[32];
        float4 g3 = *(const float4*)&ap[36];
        F8 af[4];
        af[0].u[0] = pk2h(h0.x, h0.y); af[0].u[1] = pk2h(h0.z, h0.w);
        af[0].u[2] = pk2h(h1.x, h1.y); af[0].u[3] = pk2h(h1.z, h1.w);
        af[1].u[0] = pk2h(h2.x, h2.y); af[1].u[1] = pk2h(h2.z, h2.w);
        af[1].u[2] = pk2h(h3.x, h3.y); af[1].u[3] = pk2h(h3.z, h3.w);
        af[2].u[0] = pk2h(g0.x, g0.y); af[2].u[1] = pk2h(g0.z, g0.w);
        af[2].u[2] = pk2h(g1.x, g1.y); af[2].u[3] = pk2h(g1.z, g1.w);
        af[3].u[0] = pk2h(g2.x, g2.y); af[3].u[1] = pk2h(g2.z, g2.w);
        af[3].u[2] = pk2h(g3.x, g3.y); af[3].u[3] = pk2h(g3.z, g3.w);
        float b1v[4], b2v[4];
        #pragma unroll
        for (int nt = 0; nt < 4; nt++) { b1v[nt] = B1u[nt*16+col]; b2v[nt] = B2u[nt*16+col]; }
        #pragma unroll
        for (int nt = 0; nt < 4; nt++) {
            f32x4 acc = {0.f,0.f,0.f,0.f};
            #pragma unroll
            for (int ks = 0; ks < 4; ks++) {
                F8 bf; bf.v = *(const f16x8*)&sW1u[(((ks*4+nt)*4+quad)*16+col)*8];
                acc = __builtin_amdgcn_mfma_f32_16x16x32_f16(af[ks].v, bf.v, acc, 0, 0, 0);
            }
            sAgg[(quad*4+0)*68 + nt*16+col] = fmaxf(acc.x + b1v[nt], 0.f);
            sAgg[(quad*4+1)*68 + nt*16+col] = fmaxf(acc.y + b1v[nt], 0.f);
            sAgg[(quad*4+2)*68 + nt*16+col] = fmaxf(acc.z + b1v[nt], 0.f);
            sAgg[(quad*4+3)*68 + nt*16+col] = fmaxf(acc.w + b1v[nt], 0.f);
        }
        const float* hr = &sAgg[col*68 + quad*8];
        float4 q0 = *(const float4*)&hr[0];
        float4 q1 = *(const float4*)&hr[4];
        float4 q2 = *(const float4*)&hr[32];
        float4 q3 = *(const float4*)&hr[36];
        F8 e0, e1;
        e0.u[0] = pk2h(q0.x, q0.y); e0.u[1] = pk2h(q0.z, q0.w);
        e0.u[2] = pk2h(q1.x, q1.y); e0.u[3] = pk2h(q1.z, q1.w);
        e1.u[0] = pk2h(q2.x, q2.y); e1.u[1] = pk2h(q2.z, q2.w);
        e1.u[2] = pk2h(q3.x, q3.y); e1.u[3] = pk2h(q3.z, q3.w);
        float ss[4], sq[4];
        #pragma unroll
        for (int nt = 0; nt < 4; nt++) {
            f32x4 acc = {0.f,0.f,0.f,0.f};
            F8 bf; bf.v = *(const f16x8*)&sW2u[(((0*4+nt)*4+quad)*16+col)*8];
            acc = __builtin_amdgcn_mfma_f32_16x16x32_f16(e0.v, bf.v, acc, 0, 0, 0);
            bf.v = *(const f16x8*)&sW2u[(((1*4+nt)*4+quad)*16+col)*8];
            acc = __builtin_amdgcn_mfma_f32_16x16x32_f16(e1.v, bf.v, acc, 0, 0, 0);
            float o0 = fmaxf(acc.x + b2v[nt], 0.f);
            float o1 = fmaxf(acc.y + b2v[nt], 0.f);
            float o2 = fmaxf(acc.z + b2v[nt], 0.f);
            float o3 = fmaxf(acc.w + b2v[nt], 0.f);
            h[(size_t)(n0w + quad*4 + 0)*64 + nt*16 + col] = o0;
            h[(size_t)(n0w + quad*4 + 1)*64 + nt*16 + col] = o1;
            h[(size_t)(n0w + quad*4 + 2)*64 + nt*16 + col] = o2;
            h[(size_t)(n0w + quad*4 + 3)*64 + nt*16 + col] = o3;
            ss[nt] = (o0 + o1) + (o2 + o3);
            sq[nt] = (o0*o0 + o1*o1) + (o2*o2 + o3*o3);
        }
        #pragma unroll
        for (int nt = 0; nt < 4; nt++) {
            float v = ss[nt];
            v += __shfl_down(v, 32, 64); v += __shfl_down(v, 16, 64);
            ss[nt] = v;
            float w2 = sq[nt];
            w2 += __shfl_down(w2, 32, 64); w2 += __shfl_down(w2, 16, 64);
            sq[nt] = w2;
        }
        if (lane < 16) {
            int b = (int)(blockIdx.x >> 7);
            #pragma unroll
            for (int nt = 0; nt < 4; nt++) {
                atomicAdd(&gout[b*64 + nt*16 + lane], ss[nt]);
                atomicAdd(&gout[NB*64 + b*64 + nt*16 + lane], sq[nt]);
            }
        }
    }
}

// MFMA pre (layers 1,2): normalize h (write back), A = h@W1a+b1, B = h@W1b; zero gz.
__global__ __launch_bounds__(256) void k_preM(
    float* __restrict__ h,
    const float* __restrict__ W1, const float* __restrict__ B1,
    float* __restrict__ A, float* __restrict__ Bm,
    const float* __restrict__ gin, float* __restrict__ gz)
{
    alignas(16) __shared__ _Float16 sWp[8192];   // [ks2][nt8][qd4][col16][j8]
    __shared__ float sMean[64], sRstd[64];
    for (int idx = threadIdx.x; idx < 8192; idx += 256) {
        int k = idx >> 7, n = idx & 127;
        float val = (n < 64) ? W1[k*64 + n] : W1[(64+k)*64 + (n-64)];
        int ks = k >> 5, qd = (k >> 3) & 3, j = k & 7, nt = n >> 4, cl = n & 15;
        sWp[(((ks*8+nt)*4+qd)*16+cl)*8 + j] = (_Float16)val;
    }
    if (threadIdx.x < 64) {
        int b = (int)(blockIdx.x >> 5);
        float s  = gin[b*64 + threadIdx.x];
        float qq = gin[NB*64 + b*64 + threadIdx.x];
        float mean = s * (1.f/NS);
        float var  = qq * (1.f/NS) - mean*mean;
        sMean[threadIdx.x] = mean;
        sRstd[threadIdx.x] = rsqrtf(var + EPSF);
    }
    if (blockIdx.x == 0)
        for (int i = threadIdx.x; i < 2*NB*64; i += 256) gz[i] = 0.f;
    __syncthreads();
    const int lane = threadIdx.x & 63;
    const int wv = threadIdx.x >> 6;
    const int col = lane & 15, quad = lane >> 4;
    const int n0w = blockIdx.x*64 + wv*16;
    float* hp = &h[(size_t)(n0w+col)*64 + quad*8];
    float xv[16];
    *(float4*)&xv[0]  = *(const float4*)&hp[0];
    *(float4*)&xv[4]  = *(const float4*)&hp[4];
    *(float4*)&xv[8]  = *(const float4*)&hp[32];
    *(float4*)&xv[12] = *(const float4*)&hp[36];
    #pragma unroll
    for (int t2 = 0; t2 < 8; t2++) {
        int f = quad*8 + t2;
        xv[t2] = (xv[t2] - sMean[f]) * sRstd[f];
    }
    #pragma unroll
    for (int t2 = 0; t2 < 8; t2++) {
        int f = 32 + quad*8 + t2;
        xv[8+t2] = (xv[8+t2] - sMean[f]) * sRstd[f];
    }
    *(float4*)&hp[0]  = *(float4*)&xv[0];
    *(float4*)&hp[4]  = *(float4*)&xv[4];
    *(float4*)&hp[32] = *(float4*)&xv[8];
    *(float4*)&hp[36] = *(float4*)&xv[12];
    F8 af0, af1;
    af0.u[0] = pk2h(xv[0],  xv[1]);  af0.u[1] = pk2h(xv[2],  xv[3]);
    af0.u[2] = pk2h(xv[4],  xv[5]);  af0.u[3] = pk2h(xv[6],  xv[7]);
    af1.u[0] = pk2h(xv[8],  xv[9]);  af1.u[1] = pk2h(xv[10], xv[11]);
    af1.u[2] = pk2h(xv[12], xv[13]); af1.u[3] = pk2h(xv[14], xv[15]);
    float b1v[4];
    #pragma unroll
    for (int nt = 0; nt < 4; nt++) b1v[nt] = B1[nt*16+col];
    #pragma unroll
    for (int nt = 0; nt < 8; nt++) {
        f32x4 acc = {0.f,0.f,0.f,0.f};
        F8 bf; bf.v = *(const f16x8*)&sWp[(((0*8+nt)*4+quad)*16+col)*8];
        acc = __builtin_amdgcn_mfma_f32_16x16x32_f16(af0.v, bf.v, acc, 0, 0, 0);
        bf.v = *(const f16x8*)&sWp[(((1*8+nt)*4+quad)*16+col)*8];
        acc = __builtin_amdgcn_mfma_f32_16x16x32_f16(af1.v, bf.v, acc, 0, 0, 0);
        if (nt < 4) {
            float bb = b1v[nt];
            A[(size_t)(n0w + quad*4 + 0)*64 + nt*16 + col] = acc.x + bb;
            A[(size_t)(n0w + quad*4 + 1)*64 + nt*16 + col] = acc.y + bb;
            A[(size_t)(n0w + quad*4 + 2)*64 + nt*16 + col] = acc.z + bb;
            A[(size_t)(n0w + quad*4 + 3)*64 + nt*16 + col] = acc.w + bb;
        } else {
            Bm[(size_t)(n0w + quad*4 + 0)*64 + (nt-4)*16 + col] = acc.x;
            Bm[(size_t)(n0w + quad*4 + 1)*64 + (nt-4)*16 + col] = acc.y;
            Bm[(size_t)(n0w + quad*4 + 2)*64 + (nt-4)*16 + col] = acc.z;
            Bm[(size_t)(n0w + quad*4 + 3)*64 + (nt-4)*16 + col] = acc.w;
        }
    }
}

// Fused: instance-norm + decode + sigmoid + t2-term reduction.
// 256 blocks x 64 threads (one wave) -> all CUs active.
__global__ __launch_bounds__(64) void k_dec(
    const float* __restrict__ h, const float* __restrict__ Wd, const float* __restrict__ bd,
    const float* __restrict__ g, float* __restrict__ xbuf, float* __restrict__ out1,
    float* __restrict__ accum)
{
    int n = blockIdx.x*64 + threadIdx.x;
    int b = n >> 11;
    __shared__ float sM[64], sR[64];
    __shared__ float sWd[256];
    {
        float s  = g[b*64 + threadIdx.x];
        float qq = g[NB*64 + b*64 + threadIdx.x];
        float mean = s * (1.f/NS);
        float var  = qq * (1.f/NS) - mean*mean;
        sM[threadIdx.x] = mean; sR[threadIdx.x] = rsqrtf(var + EPSF);
    }
    for (int i = threadIdx.x; i < 256; i += 64) sWd[i] = Wd[i];
    __syncthreads();
    float a0 = bd[0], a1 = bd[1], a2 = bd[2], a3 = bd[3];
    const float* hr = h + (size_t)n*64;
    #pragma unroll 8
    for (int k = 0; k < 64; k++) {
        float v = (hr[k] - sM[k]) * sR[k];
        a0 = fmaf(v, sWd[k*4+0], a0);
        a1 = fmaf(v, sWd[k*4+1], a1);
        a2 = fmaf(v, sWd[k*4+2], a2);
        a3 = fmaf(v, sWd[k*4+3], a3);
    }
    float4 o;
    o.x = 1.f/(1.f + expf(-a0));
    o.y = 1.f/(1.f + expf(-a1));
    o.z = 1.f/(1.f + expf(-a2));
    o.w = 1.f/(1.f + expf(-a3));
    *(float4*)&xbuf[(size_t)n*4] = o;
    out1[n*4+0] = o.x; out1[n*4+1] = o.y; out1[n*4+2] = o.z; out1[n*4+3] = o.w;
    float p = (1.f-o.x*o.x)*(1.f-o.y*o.y)*(1.f-o.z*o.z)*(1.f-o.w*o.w);
    for (int offs = 32; offs; offs >>= 1) p += __shfl_down(p, offs, 64);
    if (threadIdx.x == 0) atomicAdd(&accum[0], p);
}

// t3 pairwise term + final loss via last-block ticket
__global__ __launch_bounds__(256) void k_t3(const float* __restrict__ X,
                                            float* __restrict__ accum,
                                            float* __restrict__ out)
{
    int b = blockIdx.x >> 5, c = blockIdx.x & 31;
    __shared__ float sX[NS*4];
    const float* Xb = X + (size_t)b*NS*4;
    for (int idx = threadIdx.x; idx < NS*4; idx += 256) sX[idx] = Xb[idx];
    __syncthreads();
    const float4* sX4 = (const float4*)sX;
    int il = threadIdx.x & 63, wv = threadIdx.x >> 6;
    float4 xi = sX4[c*64 + il];
    float acc = 0.f;
    #pragma unroll 4
    for (int s = 0; s < 512; s++) {
        float4 xj = sX4[wv*512 + s];
        acc += (1.f - fmaxf(xi.x, xj.x)) * (1.f - fmaxf(xi.y, xj.y))
             * (1.f - fmaxf(xi.z, xj.z)) * (1.f - fmaxf(xi.w, xj.w));
    }
    for (int offs = 32; offs; offs >>= 1) acc += __shfl_down(acc, offs, 64);
    __shared__ float ws[4];
    if (il == 0) ws[wv] = acc;
    __syncthreads();
    if (threadIdx.x == 0) {
        atomicAdd(&accum[1], ws[0]+ws[1]+ws[2]+ws[3]);
        __threadfence();
        unsigned t = atomicAdd((unsigned int*)&accum[2], 1u);
        if (t == (unsigned)(NB*32 - 1)) {
            float A2 = __hip_atomic_load(&accum[0], __ATOMIC_ACQUIRE, __HIP_MEMORY_SCOPE_AGENT);
            float A3 = __hip_atomic_load(&accum[1], __ATOMIC_ACQUIRE, __HIP_MEMORY_SCOPE_AGENT);
            float t1 = 1.f/81.f;
            float t2 = (2.f/(NS*16.f)) * (A2 / NB);
            float t3 = (A3 / ((float)NS*(float)NS)) / NB;
            out[0] = t1 - t2 + t3;
        }
    }
}

extern "C" void kernel_launch(void* const* d_in, const int* in_sizes, int n_in,
                              void* d_out, int out_size, void* d_ws, size_t ws_size,
                              hipStream_t stream)
{
    const float* x     = (const float*)d_in[0];
    const int*   ei    = (const int*)d_in[1];
    const float* enc_w = (const float*)d_in[2];
    const float* enc_b = (const float*)d_in[3];
    const float* m1w   = (const float*)d_in[4];
    const float* m1b   = (const float*)d_in[5];
    const float* m2w   = (const float*)d_in[6];
    const float* m2b   = (const float*)d_in[7];
    const float* u1w   = (const float*)d_in[8];
    const float* u1b   = (const float*)d_in[9];
    const float* u2w   = (const float*)d_in[10];
    const float* u2b   = (const float*)d_in[11];
    const float* dw    = (const float*)d_in[12];
    const float* db    = (const float*)d_in[13];
    float* out = (float*)d_out;

    float* h    = (float*)d_ws;            // NN*64
    float* Apre = h    + NN*64;            // NN*64
    float* Bpre = Apre + NN*64;            // NN*64
    float* g0   = Bpre + NN*64;            // 2*NB*64
    float* g1   = g0   + 2*NB*64;          // 2*NB*64
    float* acc  = g1   + 2*NB*64;          // 4
    int*   deg  = (int*)(acc + 4);         // NN
    int*   ssrc = deg + NN;                // NN*64
    float* xbuf = Apre;                    // alias (Apre dead after last eu)

    const int* srcv = ei;
    const int* tgtv = ei + NE;
    float* gbuf[2] = {g0, g1};

    k_init<<<NN/256, 256, 0, stream>>>(deg, acc);
    k_pre0M<<<NN/64, 256, 0, stream>>>(x, enc_w, enc_b, h, m1w, m1b,
                                       Apre, Bpre, g0, srcv, tgtv, deg, ssrc);

    for (int l = 0; l < 3; l++) {
        if (l)
            k_preM<<<NN/64, 256, 0, stream>>>(h, m1w + l*128*64, m1b + l*64,
                                              Apre, Bpre,
                                              gbuf[(l+1)&1], gbuf[l&1]);
        k_eu<<<NN/16, 256, 0, stream>>>(Apre, Bpre, deg, ssrc,
                                        m2w + l*64*64, m2b + l*64,
                                        h,
                                        u1w + l*128*64, u1b + l*64,
                                        u2w + l*64*64,  u2b + l*64,
                                        gbuf[l&1]);
    }

    k_dec<<<NN/64, 64, 0, stream>>>(h, dw, db, g0, xbuf, out + 1, acc);
    k_t3<<<NB*32, 256, 0, stream>>>(xbuf, acc, out);
}

// Round 11
// 237.422 us; speedup vs baseline: 1.0581x; 1.0581x over previous
//
#include <hip/hip_runtime.h>
#include <hip/hip_fp16.h>
#include <math.h>

#define NB 8
#define NS 2048
#define NN (NB*NS)       // 16384 nodes
#define NE (NN*16)       // 262144 edges
#define EPSF 1e-5f

typedef float  f32x4 __attribute__((ext_vector_type(4)));
typedef _Float16 f16x8 __attribute__((ext_vector_type(8)));
union F8 { f16x8 v; unsigned u[4]; };

__device__ __forceinline__ unsigned pk2h(float a, float b) {
    __half2 hh = __floats2half2_rn(a, b);
    unsigned u; __builtin_memcpy(&u, &hh, 4); return u;
}

// zero deg (NN) and acc (4)
__global__ __launch_bounds__(256) void k_init(int* __restrict__ deg,
                                              float* __restrict__ acc)
{
    int i = blockIdx.x*256 + threadIdx.x;
    if (i < NN) deg[i] = 0;
    if (i < 4) acc[i] = 0.f;
}

// Layer 0 (MFMA): slotted-CSR scatter; enc -> h; A = h@W1a+b1; Bm = h@W1b; zero g0.
__global__ __launch_bounds__(256) void k_pre0M(
    const float* __restrict__ x,
    const float* __restrict__ encW, const float* __restrict__ encB,
    float* __restrict__ h,
    const float* __restrict__ W1, const float* __restrict__ B1,
    float* __restrict__ A, float* __restrict__ Bm,
    float* __restrict__ gz,
    const int* __restrict__ srcv, const int* __restrict__ tgtv,
    int* __restrict__ deg, int* __restrict__ ssrc)
{
    alignas(16) __shared__ _Float16 sWp[8192];   // [ks2][nt8][qd4][col16][j8]
    __shared__ float sEw[256], sEb[64];
    {   // slotted-CSR scatter: 4 edges per thread (256 blocks x 256 thr)
        int gid = blockIdx.x*256 + threadIdx.x;
        #pragma unroll
        for (int it = 0; it < 4; it++) {
            int e = gid + it*65536;
            int t = tgtv[e];
            int pos = atomicAdd(&deg[t], 1) & 63;
            ssrc[t*64 + pos] = srcv[e];
        }
    }
    for (int idx = threadIdx.x; idx < 8192; idx += 256) {
        int k = idx >> 7, n = idx & 127;
        float val = (n < 64) ? W1[k*64 + n] : W1[(64+k)*64 + (n-64)];
        int ks = k >> 5, qd = (k >> 3) & 3, j = k & 7, nt = n >> 4, cl = n & 15;
        sWp[(((ks*8+nt)*4+qd)*16+cl)*8 + j] = (_Float16)val;
    }
    sEw[threadIdx.x] = encW[threadIdx.x];
    if (threadIdx.x < 64) sEb[threadIdx.x] = encB[threadIdx.x];
    if (blockIdx.x == 0)
        for (int i = threadIdx.x; i < 2*NB*64; i += 256) gz[i] = 0.f;
    __syncthreads();
    const int lane = threadIdx.x & 63;
    const int wv = threadIdx.x >> 6;
    const int col = lane & 15, quad = lane >> 4;
    const int n0w = blockIdx.x*64 + wv*16;
    const int n = n0w + col;
    float4 x4 = *(const float4*)&x[(size_t)n*4];
    float xv[16];
    #pragma unroll
    for (int hh = 0; hh < 2; hh++)
        #pragma unroll
        for (int j = 0; j < 8; j++) {
            int f = hh*32 + quad*8 + j;
            float v = sEb[f];
            v = fmaf(x4.x, sEw[f],     v);
            v = fmaf(x4.y, sEw[64+f],  v);
            v = fmaf(x4.z, sEw[128+f], v);
            v = fmaf(x4.w, sEw[192+f], v);
            xv[hh*8+j] = v;
        }
    float* hp = &h[(size_t)n*64 + quad*8];
    *(float4*)&hp[0]  = *(float4*)&xv[0];
    *(float4*)&hp[4]  = *(float4*)&xv[4];
    *(float4*)&hp[32] = *(float4*)&xv[8];
    *(float4*)&hp[36] = *(float4*)&xv[12];
    F8 af0, af1;
    af0.u[0] = pk2h(xv[0],  xv[1]);  af0.u[1] = pk2h(xv[2],  xv[3]);
    af0.u[2] = pk2h(xv[4],  xv[5]);  af0.u[3] = pk2h(xv[6],  xv[7]);
    af1.u[0] = pk2h(xv[8],  xv[9]);  af1.u[1] = pk2h(xv[10], xv[11]);
    af1.u[2] = pk2h(xv[12], xv[13]); af1.u[3] = pk2h(xv[14], xv[15]);
    float b1v[4];
    #pragma unroll
    for (int nt = 0; nt < 4; nt++) b1v[nt] = B1[nt*16+col];
    #pragma unroll
    for (int nt = 0; nt < 8; nt++) {
        f32x4 acc = {0.f,0.f,0.f,0.f};
        F8 bf; bf.v = *(const f16x8*)&sWp[(((0*8+nt)*4+quad)*16+col)*8];
        acc = __builtin_amdgcn_mfma_f32_16x16x32_f16(af0.v, bf.v, acc, 0, 0, 0);
        bf.v = *(const f16x8*)&sWp[(((1*8+nt)*4+quad)*16+col)*8];
        acc = __builtin_amdgcn_mfma_f32_16x16x32_f16(af1.v, bf.v, acc, 0, 0, 0);
        if (nt < 4) {
            float bb = b1v[nt];
            A[(size_t)(n0w + quad*4 + 0)*64 + nt*16 + col] = acc.x + bb;
            A[(size_t)(n0w + quad*4 + 1)*64 + nt*16 + col] = acc.y + bb;
            A[(size_t)(n0w + quad*4 + 2)*64 + nt*16 + col] = acc.z + bb;
            A[(size_t)(n0w + quad*4 + 3)*64 + nt*16 + col] = acc.w + bb;
        } else {
            Bm[(size_t)(n0w + quad*4 + 0)*64 + (nt-4)*16 + col] = acc.x;
            Bm[(size_t)(n0w + quad*4 + 1)*64 + (nt-4)*16 + col] = acc.y;
            Bm[(size_t)(n0w + quad*4 + 2)*64 + (nt-4)*16 + col] = acc.z;
            Bm[(size_t)(n0w + quad*4 + 3)*64 + (nt-4)*16 + col] = acc.w;
        }
    }
}

// Fused edge+update: block = 16 targets; edge phase = round-9 serial version
// (proven best); update phase now split across all 4 waves (wave wv owns
// output-channel chunk nt=wv for both update layers).
__global__ __launch_bounds__(256, 4) void k_eu(
    const float* __restrict__ A, const float* __restrict__ Bm,
    const int* __restrict__ deg, const int* __restrict__ ssrc,
    const float* __restrict__ W2e, const float* __restrict__ B2e,
    float* __restrict__ h,
    const float* __restrict__ W1u, const float* __restrict__ B1u,
    const float* __restrict__ W2u, const float* __restrict__ B2u,
    float* __restrict__ gout)
{
    alignas(16) __shared__ _Float16 sW1u[8192];   // u1 packed
    alignas(16) __shared__ _Float16 sW2u[4096];   // u2 packed
    alignas(16) __shared__ _Float16 sM2[4096];    // m2 packed (edge W2)
    alignas(16) __shared__ float sAgg[16*68];     // agg tile, reused as hid tile
    for (int idx = threadIdx.x; idx < 8192; idx += 256) {
        int k = idx >> 6, n = idx & 63;
        int ks = k >> 5, qd = (k >> 3) & 3, j = k & 7, nt = n >> 4, cl = n & 15;
        sW1u[(((ks*4+nt)*4+qd)*16+cl)*8 + j] = (_Float16)W1u[idx];
    }
    for (int idx = threadIdx.x; idx < 4096; idx += 256) {
        int k = idx >> 6, n = idx & 63;
        int ks = k >> 5, qd = (k >> 3) & 3, j = k & 7, nt = n >> 4, cl = n & 15;
        sW2u[(((ks*4+nt)*4+qd)*16+cl)*8 + j] = (_Float16)W2u[idx];
        sM2 [(((ks*4+nt)*4+qd)*16+cl)*8 + j] = (_Float16)W2e[idx];
    }
    __syncthreads();
    const int lane = threadIdx.x & 63;
    const int wv = threadIdx.x >> 6;
    const int col = lane & 15, quad = lane >> 4;
    F8 bfe[4][2];
    #pragma unroll
    for (int nt = 0; nt < 4; nt++)
        #pragma unroll
        for (int ks = 0; ks < 2; ks++)
            bfe[nt][ks].v = *(const f16x8*)&sM2[(((ks*4+nt)*4+quad)*16+col)*8];
    float b2e[4];
    #pragma unroll
    for (int nt = 0; nt < 4; nt++) b2e[nt] = B2e[nt*16 + col];

    const int t_base = blockIdx.x * 16;
    int cnts[4], sv[4];
    #pragma unroll
    for (int m = 0; m < 4; m++) {
        int t = t_base + wv*4 + m;
        cnts[m] = deg[t];
        sv[m] = ssrc[t*64 + lane];
    }
    #pragma unroll
    for (int m = 0; m < 4; m++) {
        int t = t_base + wv*4 + m;
        int cnt = cnts[m] > 64 ? 64 : cnts[m];
        const float* ar = &A[(size_t)t*64 + quad*8];
        float4 a0 = *(const float4*)&ar[0];
        float4 a1 = *(const float4*)&ar[4];
        float4 a2 = *(const float4*)&ar[32];
        float4 a3 = *(const float4*)&ar[36];
        float cs[4] = {0.f, 0.f, 0.f, 0.f};
        for (int s0 = 0; s0 < cnt; s0 += 16) {
            int v = cnt - s0;
            int cc = col < v-1 ? col : v-1;
            int sr = __shfl(sv[m], s0 + cc, 64);
            const float* br = &Bm[(size_t)sr*64 + quad*8];
            float4 b0 = *(const float4*)&br[0];
            float4 b1 = *(const float4*)&br[4];
            float4 b2_ = *(const float4*)&br[32];
            float4 b3 = *(const float4*)&br[36];
            F8 af0, af1;
            af0.u[0] = pk2h(fmaxf(a0.x+b0.x,0.f), fmaxf(a0.y+b0.y,0.f));
            af0.u[1] = pk2h(fmaxf(a0.z+b0.z,0.f), fmaxf(a0.w+b0.w,0.f));
            af0.u[2] = pk2h(fmaxf(a1.x+b1.x,0.f), fmaxf(a1.y+b1.y,0.f));
            af0.u[3] = pk2h(fmaxf(a1.z+b1.z,0.f), fmaxf(a1.w+b1.w,0.f));
            af1.u[0] = pk2h(fmaxf(a2.x+b2_.x,0.f), fmaxf(a2.y+b2_.y,0.f));
            af1.u[1] = pk2h(fmaxf(a2.z+b2_.z,0.f), fmaxf(a2.w+b2_.w,0.f));
            af1.u[2] = pk2h(fmaxf(a3.x+b3.x,0.f), fmaxf(a3.y+b3.y,0.f));
            af1.u[3] = pk2h(fmaxf(a3.z+b3.z,0.f), fmaxf(a3.w+b3.w,0.f));
            #pragma unroll
            for (int nt = 0; nt < 4; nt++) {
                f32x4 acc = __builtin_amdgcn_mfma_f32_16x16x32_f16(
                                af0.v, bfe[nt][0].v, (f32x4){0.f,0.f,0.f,0.f}, 0, 0, 0);
                acc = __builtin_amdgcn_mfma_f32_16x16x32_f16(
                                af1.v, bfe[nt][1].v, acc, 0, 0, 0);
                float r0 = (quad*4+0 < v) ? fmaxf(acc.x + b2e[nt], 0.f) : 0.f;
                float r1 = (quad*4+1 < v) ? fmaxf(acc.y + b2e[nt], 0.f) : 0.f;
                float r2 = (quad*4+2 < v) ? fmaxf(acc.z + b2e[nt], 0.f) : 0.f;
                float r3 = (quad*4+3 < v) ? fmaxf(acc.w + b2e[nt], 0.f) : 0.f;
                cs[nt] += (r0 + r1) + (r2 + r3);
            }
        }
        #pragma unroll
        for (int nt = 0; nt < 4; nt++) {
            float vv = cs[nt];
            vv += __shfl_down(vv, 32, 64);
            vv += __shfl_down(vv, 16, 64);
            cs[nt] = vv;
        }
        if (lane < 16) {
            sAgg[(wv*4+m)*68 +  0 + lane] = cs[0];
            sAgg[(wv*4+m)*68 + 16 + lane] = cs[1];
            sAgg[(wv*4+m)*68 + 32 + lane] = cs[2];
            sAgg[(wv*4+m)*68 + 48 + lane] = cs[3];
        }
    }
    __syncthreads();
    // ---- update phase: all 4 waves; wave wv owns output-channel chunk nt=wv ----
    const int n0w = t_base;
    const float* hp = &h[(size_t)(n0w+col)*64 + quad*8];
    float4 h0 = *(const float4*)&hp[0];
    float4 h1 = *(const float4*)&hp[4];
    float4 h2 = *(const float4*)&hp[32];
    float4 h3 = *(const float4*)&hp[36];
    const float* ap = &sAgg[col*68 + quad*8];
    float4 g0 = *(const float4*)&ap[0];
    float4 g1 = *(const float4*)&ap[4];
    float4 g2 = *(const float4*)&ap[32];
    float4 g3 = *(const float4*)&ap[36];
    F8 af[4];
    af[0].u[0] = pk2h(h0.x, h0.y); af[0].u[1] = pk2h(h0.z, h0.w);
    af[0].u[2] = pk2h(h1.x, h1.y); af[0].u[3] = pk2h(h1.z, h1.w);
    af[1].u[0] = pk2h(h2.x, h2.y); af[1].u[1] = pk2h(h2.z, h2.w);
    af[1].u[2] = pk2h(h3.x, h3.y); af[1].u[3] = pk2h(h3.z, h3.w);
    af[2].u[0] = pk2h(g0.x, g0.y); af[2].u[1] = pk2h(g0.z, g0.w);
    af[2].u[2] = pk2h(g1.x, g1.y); af[2].u[3] = pk2h(g1.z, g1.w);
    af[3].u[0] = pk2h(g2.x, g2.y); af[3].u[1] = pk2h(g2.z, g2.w);
    af[3].u[2] = pk2h(g3.x, g3.y); af[3].u[3] = pk2h(g3.z, g3.w);
    const float b1v = B1u[wv*16+col];
    const float b2v = B2u[wv*16+col];
    __syncthreads();   // all g reads done before hid overwrite
    {   // u1: this wave's 16-col chunk
        f32x4 acc = {0.f,0.f,0.f,0.f};
        #pragma unroll
        for (int ks = 0; ks < 4; ks++) {
            F8 bf; bf.v = *(const f16x8*)&sW1u[(((ks*4+wv)*4+quad)*16+col)*8];
            acc = __builtin_amdgcn_mfma_f32_16x16x32_f16(af[ks].v, bf.v, acc, 0, 0, 0);
        }
        sAgg[(quad*4+0)*68 + wv*16+col] = fmaxf(acc.x + b1v, 0.f);
        sAgg[(quad*4+1)*68 + wv*16+col] = fmaxf(acc.y + b1v, 0.f);
        sAgg[(quad*4+2)*68 + wv*16+col] = fmaxf(acc.z + b1v, 0.f);
        sAgg[(quad*4+3)*68 + wv*16+col] = fmaxf(acc.w + b1v, 0.f);
    }
    __syncthreads();
    {   // u2: read full hid rows, compute this wave's 16-col chunk
        const float* hr = &sAgg[col*68 + quad*8];
        float4 q0 = *(const float4*)&hr[0];
        float4 q1 = *(const float4*)&hr[4];
        float4 q2 = *(const float4*)&hr[32];
        float4 q3 = *(const float4*)&hr[36];
        F8 e0, e1;
        e0.u[0] = pk2h(q0.x, q0.y); e0.u[1] = pk2h(q0.z, q0.w);
        e0.u[2] = pk2h(q1.x, q1.y); e0.u[3] = pk2h(q1.z, q1.w);
        e1.u[0] = pk2h(q2.x, q2.y); e1.u[1] = pk2h(q2.z, q2.w);
        e1.u[2] = pk2h(q3.x, q3.y); e1.u[3] = pk2h(q3.z, q3.w);
        f32x4 acc = {0.f,0.f,0.f,0.f};
        F8 bf; bf.v = *(const f16x8*)&sW2u[(((0*4+wv)*4+quad)*16+col)*8];
        acc = __builtin_amdgcn_mfma_f32_16x16x32_f16(e0.v, bf.v, acc, 0, 0, 0);
        bf.v = *(const f16x8*)&sW2u[(((1*4+wv)*4+quad)*16+col)*8];
        acc = __builtin_amdgcn_mfma_f32_16x16x32_f16(e1.v, bf.v, acc, 0, 0, 0);
        float o0 = fmaxf(acc.x + b2v, 0.f);
        float o1 = fmaxf(acc.y + b2v, 0.f);
        float o2 = fmaxf(acc.z + b2v, 0.f);
        float o3 = fmaxf(acc.w + b2v, 0.f);
        h[(size_t)(n0w + quad*4 + 0)*64 + wv*16 + col] = o0;
        h[(size_t)(n0w + quad*4 + 1)*64 + wv*16 + col] = o1;
        h[(size_t)(n0w + quad*4 + 2)*64 + wv*16 + col] = o2;
        h[(size_t)(n0w + quad*4 + 3)*64 + wv*16 + col] = o3;
        float ss = (o0 + o1) + (o2 + o3);
        float sq = (o0*o0 + o1*o1) + (o2*o2 + o3*o3);
        ss += __shfl_down(ss, 32, 64); ss += __shfl_down(ss, 16, 64);
        sq += __shfl_down(sq, 32, 64); sq += __shfl_down(sq, 16, 64);
        if (lane < 16) {
            int b = (int)(blockIdx.x >> 7);
            atomicAdd(&gout[b*64 + wv*16 + lane], ss);
            atomicAdd(&gout[NB*64 + b*64 + wv*16 + lane], sq);
        }
    }
}

// MFMA pre (layers 1,2): normalize h (write back), A = h@W1a+b1, B = h@W1b; zero gz.
__global__ __launch_bounds__(256) void k_preM(
    float* __restrict__ h,
    const float* __restrict__ W1, const float* __restrict__ B1,
    float* __restrict__ A, float* __restrict__ Bm,
    const float* __restrict__ gin, float* __restrict__ gz)
{
    alignas(16) __shared__ _Float16 sWp[8192];   // [ks2][nt8][qd4][col16][j8]
    __shared__ float sMean[64], sRstd[64];
    for (int idx = threadIdx.x; idx < 8192; idx += 256) {
        int k = idx >> 7, n = idx & 127;
        float val = (n < 64) ? W1[k*64 + n] : W1[(64+k)*64 + (n-64)];
        int ks = k >> 5, qd = (k >> 3) & 3, j = k & 7, nt = n >> 4, cl = n & 15;
        sWp[(((ks*8+nt)*4+qd)*16+cl)*8 + j] = (_Float16)val;
    }
    if (threadIdx.x < 64) {
        int b = (int)(blockIdx.x >> 5);
        float s  = gin[b*64 + threadIdx.x];
        float qq = gin[NB*64 + b*64 + threadIdx.x];
        float mean = s * (1.f/NS);
        float var  = qq * (1.f/NS) - mean*mean;
        sMean[threadIdx.x] = mean;
        sRstd[threadIdx.x] = rsqrtf(var + EPSF);
    }
    if (blockIdx.x == 0)
        for (int i = threadIdx.x; i < 2*NB*64; i += 256) gz[i] = 0.f;
    __syncthreads();
    const int lane = threadIdx.x & 63;
    const int wv = threadIdx.x >> 6;
    const int col = lane & 15, quad = lane >> 4;
    const int n0w = blockIdx.x*64 + wv*16;
    float* hp = &h[(size_t)(n0w+col)*64 + quad*8];
    float xv[16];
    *(float4*)&xv[0]  = *(const float4*)&hp[0];
    *(float4*)&xv[4]  = *(const float4*)&hp[4];
    *(float4*)&xv[8]  = *(const float4*)&hp[32];
    *(float4*)&xv[12] = *(const float4*)&hp[36];
    #pragma unroll
    for (int t2 = 0; t2 < 8; t2++) {
        int f = quad*8 + t2;
        xv[t2] = (xv[t2] - sMean[f]) * sRstd[f];
    }
    #pragma unroll
    for (int t2 = 0; t2 < 8; t2++) {
        int f = 32 + quad*8 + t2;
        xv[8+t2] = (xv[8+t2] - sMean[f]) * sRstd[f];
    }
    *(float4*)&hp[0]  = *(float4*)&xv[0];
    *(float4*)&hp[4]  = *(float4*)&xv[4];
    *(float4*)&hp[32] = *(float4*)&xv[8];
    *(float4*)&hp[36] = *(float4*)&xv[12];
    F8 af0, af1;
    af0.u[0] = pk2h(xv[0],  xv[1]);  af0.u[1] = pk2h(xv[2],  xv[3]);
    af0.u[2] = pk2h(xv[4],  xv[5]);  af0.u[3] = pk2h(xv[6],  xv[7]);
    af1.u[0] = pk2h(xv[8],  xv[9]);  af1.u[1] = pk2h(xv[10], xv[11]);
    af1.u[2] = pk2h(xv[12], xv[13]); af1.u[3] = pk2h(xv[14], xv[15]);
    float b1v[4];
    #pragma unroll
    for (int nt = 0; nt < 4; nt++) b1v[nt] = B1[nt*16+col];
    #pragma unroll
    for (int nt = 0; nt < 8; nt++) {
        f32x4 acc = {0.f,0.f,0.f,0.f};
        F8 bf; bf.v = *(const f16x8*)&sWp[(((0*8+nt)*4+quad)*16+col)*8];
        acc = __builtin_amdgcn_mfma_f32_16x16x32_f16(af0.v, bf.v, acc, 0, 0, 0);
        bf.v = *(const f16x8*)&sWp[(((1*8+nt)*4+quad)*16+col)*8];
        acc = __builtin_amdgcn_mfma_f32_16x16x32_f16(af1.v, bf.v, acc, 0, 0, 0);
        if (nt < 4) {
            float bb = b1v[nt];
            A[(size_t)(n0w + quad*4 + 0)*64 + nt*16 + col] = acc.x + bb;
            A[(size_t)(n0w + quad*4 + 1)*64 + nt*16 + col] = acc.y + bb;
            A[(size_t)(n0w + quad*4 + 2)*64 + nt*16 + col] = acc.z + bb;
            A[(size_t)(n0w + quad*4 + 3)*64 + nt*16 + col] = acc.w + bb;
        } else {
            Bm[(size_t)(n0w + quad*4 + 0)*64 + (nt-4)*16 + col] = acc.x;
            Bm[(size_t)(n0w + quad*4 + 1)*64 + (nt-4)*16 + col] = acc.y;
            Bm[(size_t)(n0w + quad*4 + 2)*64 + (nt-4)*16 + col] = acc.z;
            Bm[(size_t)(n0w + quad*4 + 3)*64 + (nt-4)*16 + col] = acc.w;
        }
    }
}

// Fused: instance-norm + decode + sigmoid + t2-term reduction.
// 256 blocks x 64 threads (one wave) -> all CUs active.
__global__ __launch_bounds__(64) void k_dec(
    const float* __restrict__ h, const float* __restrict__ Wd, const float* __restrict__ bd,
    const float* __restrict__ g, float* __restrict__ xbuf, float* __restrict__ out1,
    float* __restrict__ accum)
{
    int n = blockIdx.x*64 + threadIdx.x;
    int b = n >> 11;
    __shared__ float sM[64], sR[64];
    __shared__ float sWd[256];
    {
        float s  = g[b*64 + threadIdx.x];
        float qq = g[NB*64 + b*64 + threadIdx.x];
        float mean = s * (1.f/NS);
        float var  = qq * (1.f/NS) - mean*mean;
        sM[threadIdx.x] = mean; sR[threadIdx.x] = rsqrtf(var + EPSF);
    }
    for (int i = threadIdx.x; i < 256; i += 64) sWd[i] = Wd[i];
    __syncthreads();
    float a0 = bd[0], a1 = bd[1], a2 = bd[2], a3 = bd[3];
    const float* hr = h + (size_t)n*64;
    #pragma unroll 8
    for (int k = 0; k < 64; k++) {
        float v = (hr[k] - sM[k]) * sR[k];
        a0 = fmaf(v, sWd[k*4+0], a0);
        a1 = fmaf(v, sWd[k*4+1], a1);
        a2 = fmaf(v, sWd[k*4+2], a2);
        a3 = fmaf(v, sWd[k*4+3], a3);
    }
    float4 o;
    o.x = 1.f/(1.f + expf(-a0));
    o.y = 1.f/(1.f + expf(-a1));
    o.z = 1.f/(1.f + expf(-a2));
    o.w = 1.f/(1.f + expf(-a3));
    *(float4*)&xbuf[(size_t)n*4] = o;
    out1[n*4+0] = o.x; out1[n*4+1] = o.y; out1[n*4+2] = o.z; out1[n*4+3] = o.w;
    float p = (1.f-o.x*o.x)*(1.f-o.y*o.y)*(1.f-o.z*o.z)*(1.f-o.w*o.w);
    for (int offs = 32; offs; offs >>= 1) p += __shfl_down(p, offs, 64);
    if (threadIdx.x == 0) atomicAdd(&accum[0], p);
}

// t3 pairwise term (2 xi rows per thread) + final loss via last-block ticket
__global__ __launch_bounds__(256) void k_t3(const float* __restrict__ X,
                                            float* __restrict__ accum,
                                            float* __restrict__ out)
{
    int b = blockIdx.x >> 4, c = blockIdx.x & 15;   // 8 graphs x 16 i-chunks of 128
    __shared__ float sX[NS*4];
    const float* Xb = X + (size_t)b*NS*4;
    for (int idx = threadIdx.x; idx < NS*4; idx += 256) sX[idx] = Xb[idx];
    __syncthreads();
    const float4* sX4 = (const float4*)sX;
    int il = threadIdx.x & 63, wv = threadIdx.x >> 6;
    float4 xiA = sX4[(c*2+0)*64 + il];
    float4 xiB = sX4[(c*2+1)*64 + il];
    float accA = 0.f, accB = 0.f;
    #pragma unroll 4
    for (int s = 0; s < 512; s++) {
        float4 xj = sX4[wv*512 + s];
        accA += (1.f - fmaxf(xiA.x, xj.x)) * (1.f - fmaxf(xiA.y, xj.y))
              * (1.f - fmaxf(xiA.z, xj.z)) * (1.f - fmaxf(xiA.w, xj.w));
        accB += (1.f - fmaxf(xiB.x, xj.x)) * (1.f - fmaxf(xiB.y, xj.y))
              * (1.f - fmaxf(xiB.z, xj.z)) * (1.f - fmaxf(xiB.w, xj.w));
    }
    float acc = accA + accB;
    for (int offs = 32; offs; offs >>= 1) acc += __shfl_down(acc, offs, 64);
    __shared__ float ws[4];
    if (il == 0) ws[wv] = acc;
    __syncthreads();
    if (threadIdx.x == 0) {
        atomicAdd(&accum[1], ws[0]+ws[1]+ws[2]+ws[3]);
        __threadfence();
        unsigned t = atomicAdd((unsigned int*)&accum[2], 1u);
        if (t == (unsigned)(NB*16 - 1)) {
            float A2 = __hip_atomic_load(&accum[0], __ATOMIC_ACQUIRE, __HIP_MEMORY_SCOPE_AGENT);
            float A3 = __hip_atomic_load(&accum[1], __ATOMIC_ACQUIRE, __HIP_MEMORY_SCOPE_AGENT);
            float t1 = 1.f/81.f;
            float t2 = (2.f/(NS*16.f)) * (A2 / NB);
            float t3 = (A3 / ((float)NS*(float)NS)) / NB;
            out[0] = t1 - t2 + t3;
        }
    }
}

extern "C" void kernel_launch(void* const* d_in, const int* in_sizes, int n_in,
                              void* d_out, int out_size, void* d_ws, size_t ws_size,
                              hipStream_t stream)
{
    const float* x     = (const float*)d_in[0];
    const int*   ei    = (const int*)d_in[1];
    const float* enc_w = (const float*)d_in[2];
    const float* enc_b = (const float*)d_in[3];
    const float* m1w   = (const float*)d_in[4];
    const float* m1b   = (const float*)d_in[5];
    const float* m2w   = (const float*)d_in[6];
    const float* m2b   = (const float*)d_in[7];
    const float* u1w   = (const float*)d_in[8];
    const float* u1b   = (const float*)d_in[9];
    const float* u2w   = (const float*)d_in[10];
    const float* u2b   = (const float*)d_in[11];
    const float* dw    = (const float*)d_in[12];
    const float* db    = (const float*)d_in[13];
    float* out = (float*)d_out;

    float* h    = (float*)d_ws;            // NN*64
    float* Apre = h    + NN*64;            // NN*64
    float* Bpre = Apre + NN*64;            // NN*64
    float* g0   = Bpre + NN*64;            // 2*NB*64
    float* g1   = g0   + 2*NB*64;          // 2*NB*64
    float* acc  = g1   + 2*NB*64;          // 4
    int*   deg  = (int*)(acc + 4);         // NN
    int*   ssrc = deg + NN;                // NN*64
    float* xbuf = Apre;                    // alias (Apre dead after last eu)

    const int* srcv = ei;
    const int* tgtv = ei + NE;
    float* gbuf[2] = {g0, g1};

    k_init<<<NN/256, 256, 0, stream>>>(deg, acc);
    k_pre0M<<<NN/64, 256, 0, stream>>>(x, enc_w, enc_b, h, m1w, m1b,
                                       Apre, Bpre, g0, srcv, tgtv, deg, ssrc);

    for (int l = 0; l < 3; l++) {
        if (l)
            k_preM<<<NN/64, 256, 0, stream>>>(h, m1w + l*128*64, m1b + l*64,
                                              Apre, Bpre,
                                              gbuf[(l+1)&1], gbuf[l&1]);
        k_eu<<<NN/16, 256, 0, stream>>>(Apre, Bpre, deg, ssrc,
                                        m2w + l*64*64, m2b + l*64,
                                        h,
                                        u1w + l*128*64, u1b + l*64,
                                        u2w + l*64*64,  u2b + l*64,
                                        gbuf[l&1]);
    }

    k_dec<<<NN/64, 64, 0, stream>>>(h, dw, db, g0, xbuf, out + 1, acc);
    k_t3<<<NB*16, 256, 0, stream>>>(xbuf, acc, out);
}

// Round 12
// 221.456 us; speedup vs baseline: 1.1344x; 1.0721x over previous
//
#include <hip/hip_runtime.h>
#include <hip/hip_fp16.h>
#include <math.h>

#define NB 8
#define NS 2048
#define NN (NB*NS)       // 16384 nodes
#define NE (NN*16)       // 262144 edges
#define EPSF 1e-5f

typedef float  f32x4 __attribute__((ext_vector_type(4)));
typedef _Float16 f16x8 __attribute__((ext_vector_type(8)));
union F8 { f16x8 v; unsigned u[4]; };

__device__ __forceinline__ unsigned pk2h(float a, float b) {
    __half2 hh = __floats2half2_rn(a, b);
    unsigned u; __builtin_memcpy(&u, &hh, 4); return u;
}

__device__ __forceinline__ f16x8 relu8(f16x8 v) {
    #pragma unroll
    for (int i = 0; i < 8; i++) v[i] = v[i] > (_Float16)0.f ? v[i] : (_Float16)0.f;
    return v;
}

// zero deg (NN) and acc (4)
__global__ __launch_bounds__(256) void k_init(int* __restrict__ deg,
                                              float* __restrict__ acc)
{
    int i = blockIdx.x*256 + threadIdx.x;
    if (i < NN) deg[i] = 0;
    if (i < 4) acc[i] = 0.f;
}

// Layer 0 (MFMA): slotted-CSR scatter; enc -> h; A = h@W1a+b1 (f16); Bm = h@W1b (f16); zero g0.
__global__ __launch_bounds__(256) void k_pre0M(
    const float* __restrict__ x,
    const float* __restrict__ encW, const float* __restrict__ encB,
    float* __restrict__ h,
    const float* __restrict__ W1, const float* __restrict__ B1,
    _Float16* __restrict__ A, _Float16* __restrict__ Bm,
    float* __restrict__ gz,
    const int* __restrict__ srcv, const int* __restrict__ tgtv,
    int* __restrict__ deg, int* __restrict__ ssrc)
{
    alignas(16) __shared__ _Float16 sWp[8192];   // [ks2][nt8][qd4][col16][j8]
    __shared__ float sEw[256], sEb[64];
    {   // slotted-CSR scatter: 4 edges per thread (256 blocks x 256 thr)
        int gid = blockIdx.x*256 + threadIdx.x;
        #pragma unroll
        for (int it = 0; it < 4; it++) {
            int e = gid + it*65536;
            int t = tgtv[e];
            int pos = atomicAdd(&deg[t], 1) & 63;
            ssrc[t*64 + pos] = srcv[e];
        }
    }
    for (int idx = threadIdx.x; idx < 8192; idx += 256) {
        int k = idx >> 7, n = idx & 127;
        float val = (n < 64) ? W1[k*64 + n] : W1[(64+k)*64 + (n-64)];
        int ks = k >> 5, qd = (k >> 3) & 3, j = k & 7, nt = n >> 4, cl = n & 15;
        sWp[(((ks*8+nt)*4+qd)*16+cl)*8 + j] = (_Float16)val;
    }
    sEw[threadIdx.x] = encW[threadIdx.x];
    if (threadIdx.x < 64) sEb[threadIdx.x] = encB[threadIdx.x];
    if (blockIdx.x == 0)
        for (int i = threadIdx.x; i < 2*NB*64; i += 256) gz[i] = 0.f;
    __syncthreads();
    const int lane = threadIdx.x & 63;
    const int wv = threadIdx.x >> 6;
    const int col = lane & 15, quad = lane >> 4;
    const int n0w = blockIdx.x*64 + wv*16;
    const int n = n0w + col;
    float4 x4 = *(const float4*)&x[(size_t)n*4];
    float xv[16];
    #pragma unroll
    for (int hh = 0; hh < 2; hh++)
        #pragma unroll
        for (int j = 0; j < 8; j++) {
            int f = hh*32 + quad*8 + j;
            float v = sEb[f];
            v = fmaf(x4.x, sEw[f],     v);
            v = fmaf(x4.y, sEw[64+f],  v);
            v = fmaf(x4.z, sEw[128+f], v);
            v = fmaf(x4.w, sEw[192+f], v);
            xv[hh*8+j] = v;
        }
    float* hp = &h[(size_t)n*64 + quad*8];
    *(float4*)&hp[0]  = *(float4*)&xv[0];
    *(float4*)&hp[4]  = *(float4*)&xv[4];
    *(float4*)&hp[32] = *(float4*)&xv[8];
    *(float4*)&hp[36] = *(float4*)&xv[12];
    F8 af0, af1;
    af0.u[0] = pk2h(xv[0],  xv[1]);  af0.u[1] = pk2h(xv[2],  xv[3]);
    af0.u[2] = pk2h(xv[4],  xv[5]);  af0.u[3] = pk2h(xv[6],  xv[7]);
    af1.u[0] = pk2h(xv[8],  xv[9]);  af1.u[1] = pk2h(xv[10], xv[11]);
    af1.u[2] = pk2h(xv[12], xv[13]); af1.u[3] = pk2h(xv[14], xv[15]);
    float b1v[4];
    #pragma unroll
    for (int nt = 0; nt < 4; nt++) b1v[nt] = B1[nt*16+col];
    #pragma unroll
    for (int nt = 0; nt < 8; nt++) {
        f32x4 acc = {0.f,0.f,0.f,0.f};
        F8 bf; bf.v = *(const f16x8*)&sWp[(((0*8+nt)*4+quad)*16+col)*8];
        acc = __builtin_amdgcn_mfma_f32_16x16x32_f16(af0.v, bf.v, acc, 0, 0, 0);
        bf.v = *(const f16x8*)&sWp[(((1*8+nt)*4+quad)*16+col)*8];
        acc = __builtin_amdgcn_mfma_f32_16x16x32_f16(af1.v, bf.v, acc, 0, 0, 0);
        if (nt < 4) {
            float bb = b1v[nt];
            A[(size_t)(n0w + quad*4 + 0)*64 + nt*16 + col] = (_Float16)(acc.x + bb);
            A[(size_t)(n0w + quad*4 + 1)*64 + nt*16 + col] = (_Float16)(acc.y + bb);
            A[(size_t)(n0w + quad*4 + 2)*64 + nt*16 + col] = (_Float16)(acc.z + bb);
            A[(size_t)(n0w + quad*4 + 3)*64 + nt*16 + col] = (_Float16)(acc.w + bb);
        } else {
            Bm[(size_t)(n0w + quad*4 + 0)*64 + (nt-4)*16 + col] = (_Float16)acc.x;
            Bm[(size_t)(n0w + quad*4 + 1)*64 + (nt-4)*16 + col] = (_Float16)acc.y;
            Bm[(size_t)(n0w + quad*4 + 2)*64 + (nt-4)*16 + col] = (_Float16)acc.z;
            Bm[(size_t)(n0w + quad*4 + 3)*64 + (nt-4)*16 + col] = (_Float16)acc.w;
        }
    }
}

// Fused edge+update (round-9 structure): block = 16 targets; 4 waves x 4 targets
// edge MFMA -> LDS agg tile; wave 0 runs the 16-node update MLP from LDS.
// A/Bm are f16: gathers are 16 B/lane and fragments need no fp32->f16 pack.
__global__ __launch_bounds__(256, 4) void k_eu(
    const _Float16* __restrict__ A, const _Float16* __restrict__ Bm,
    const int* __restrict__ deg, const int* __restrict__ ssrc,
    const float* __restrict__ W2e, const float* __restrict__ B2e,
    float* __restrict__ h,
    const float* __restrict__ W1u, const float* __restrict__ B1u,
    const float* __restrict__ W2u, const float* __restrict__ B2u,
    float* __restrict__ gout)
{
    alignas(16) __shared__ _Float16 sW1u[8192];   // u1 packed
    alignas(16) __shared__ _Float16 sW2u[4096];   // u2 packed
    alignas(16) __shared__ _Float16 sM2[4096];    // m2 packed (edge W2)
    alignas(16) __shared__ float sAgg[16*68];     // agg tile, reused as hid tile
    for (int idx = threadIdx.x; idx < 8192; idx += 256) {
        int k = idx >> 6, n = idx & 63;
        int ks = k >> 5, qd = (k >> 3) & 3, j = k & 7, nt = n >> 4, cl = n & 15;
        sW1u[(((ks*4+nt)*4+qd)*16+cl)*8 + j] = (_Float16)W1u[idx];
    }
    for (int idx = threadIdx.x; idx < 4096; idx += 256) {
        int k = idx >> 6, n = idx & 63;
        int ks = k >> 5, qd = (k >> 3) & 3, j = k & 7, nt = n >> 4, cl = n & 15;
        sW2u[(((ks*4+nt)*4+qd)*16+cl)*8 + j] = (_Float16)W2u[idx];
        sM2 [(((ks*4+nt)*4+qd)*16+cl)*8 + j] = (_Float16)W2e[idx];
    }
    __syncthreads();
    const int lane = threadIdx.x & 63;
    const int wv = threadIdx.x >> 6;
    const int col = lane & 15, quad = lane >> 4;
    F8 bfe[4][2];
    #pragma unroll
    for (int nt = 0; nt < 4; nt++)
        #pragma unroll
        for (int ks = 0; ks < 2; ks++)
            bfe[nt][ks].v = *(const f16x8*)&sM2[(((ks*4+nt)*4+quad)*16+col)*8];
    float b2e[4];
    #pragma unroll
    for (int nt = 0; nt < 4; nt++) b2e[nt] = B2e[nt*16 + col];

    const int t_base = blockIdx.x * 16;
    int cnts[4], sv[4];
    #pragma unroll
    for (int m = 0; m < 4; m++) {
        int t = t_base + wv*4 + m;
        cnts[m] = deg[t];
        sv[m] = ssrc[t*64 + lane];
    }
    #pragma unroll
    for (int m = 0; m < 4; m++) {
        int t = t_base + wv*4 + m;
        int cnt = cnts[m] > 64 ? 64 : cnts[m];
        const _Float16* ar = &A[(size_t)t*64 + quad*8];
        f16x8 aLo = *(const f16x8*)&ar[0];    // k = quad*8 .. +7
        f16x8 aHi = *(const f16x8*)&ar[32];   // k = 32+quad*8 .. +7
        float cs[4] = {0.f, 0.f, 0.f, 0.f};
        for (int s0 = 0; s0 < cnt; s0 += 16) {
            int v = cnt - s0;
            int cc = col < v-1 ? col : v-1;
            int sr = __shfl(sv[m], s0 + cc, 64);
            const _Float16* br = &Bm[(size_t)sr*64 + quad*8];
            f16x8 bLo = *(const f16x8*)&br[0];
            f16x8 bHi = *(const f16x8*)&br[32];
            F8 af0, af1;
            af0.v = relu8(aLo + bLo);
            af1.v = relu8(aHi + bHi);
            #pragma unroll
            for (int nt = 0; nt < 4; nt++) {
                f32x4 acc = __builtin_amdgcn_mfma_f32_16x16x32_f16(
                                af0.v, bfe[nt][0].v, (f32x4){0.f,0.f,0.f,0.f}, 0, 0, 0);
                acc = __builtin_amdgcn_mfma_f32_16x16x32_f16(
                                af1.v, bfe[nt][1].v, acc, 0, 0, 0);
                float r0 = (quad*4+0 < v) ? fmaxf(acc.x + b2e[nt], 0.f) : 0.f;
                float r1 = (quad*4+1 < v) ? fmaxf(acc.y + b2e[nt], 0.f) : 0.f;
                float r2 = (quad*4+2 < v) ? fmaxf(acc.z + b2e[nt], 0.f) : 0.f;
                float r3 = (quad*4+3 < v) ? fmaxf(acc.w + b2e[nt], 0.f) : 0.f;
                cs[nt] += (r0 + r1) + (r2 + r3);
            }
        }
        #pragma unroll
        for (int nt = 0; nt < 4; nt++) {
            float vv = cs[nt];
            vv += __shfl_down(vv, 32, 64);
            vv += __shfl_down(vv, 16, 64);
            cs[nt] = vv;
        }
        if (lane < 16) {
            sAgg[(wv*4+m)*68 +  0 + lane] = cs[0];
            sAgg[(wv*4+m)*68 + 16 + lane] = cs[1];
            sAgg[(wv*4+m)*68 + 32 + lane] = cs[2];
            sAgg[(wv*4+m)*68 + 48 + lane] = cs[3];
        }
    }
    __syncthreads();
    if (wv == 0) {
        const int n0w = t_base;
        const float* hp = &h[(size_t)(n0w+col)*64 + quad*8];
        float4 h0 = *(const float4*)&hp[0];
        float4 h1 = *(const float4*)&hp[4];
        float4 h2 = *(const float4*)&hp[32];
        float4 h3 = *(const float4*)&hp[36];
        const float* ap = &sAgg[col*68 + quad*8];
        float4 g0 = *(const float4*)&ap[0];
        float4 g1 = *(const float4*)&ap[4];
        float4 g2 = *(const float4*)&ap[32];
        float4 g3 = *(const float4*)&ap[36];
        F8 af[4];
        af[0].u[0] = pk2h(h0.x, h0.y); af[0].u[1] = pk2h(h0.z, h0.w);
        af[0].u[2] = pk2h(h1.x, h1.y); af[0].u[3] = pk2h(h1.z, h1.w);
        af[1].u[0] = pk2h(h2.x, h2.y); af[1].u[1] = pk2h(h2.z, h2.w);
        af[1].u[2] = pk2h(h3.x, h3.y); af[1].u[3] = pk2h(h3.z, h3.w);
        af[2].u[0] = pk2h(g0.x, g0.y); af[2].u[1] = pk2h(g0.z, g0.w);
        af[2].u[2] = pk2h(g1.x, g1.y); af[2].u[3] = pk2h(g1.z, g1.w);
        af[3].u[0] = pk2h(g2.x, g2.y); af[3].u[1] = pk2h(g2.z, g2.w);
        af[3].u[2] = pk2h(g3.x, g3.y); af[3].u[3] = pk2h(g3.z, g3.w);
        float b1v[4], b2v[4];
        #pragma unroll
        for (int nt = 0; nt < 4; nt++) { b1v[nt] = B1u[nt*16+col]; b2v[nt] = B2u[nt*16+col]; }
        #pragma unroll
        for (int nt = 0; nt < 4; nt++) {
            f32x4 acc = {0.f,0.f,0.f,0.f};
            #pragma unroll
            for (int ks = 0; ks < 4; ks++) {
                F8 bf; bf.v = *(const f16x8*)&sW1u[(((ks*4+nt)*4+quad)*16+col)*8];
                acc = __builtin_amdgcn_mfma_f32_16x16x32_f16(af[ks].v, bf.v, acc, 0, 0, 0);
            }
            sAgg[(quad*4+0)*68 + nt*16+col] = fmaxf(acc.x + b1v[nt], 0.f);
            sAgg[(quad*4+1)*68 + nt*16+col] = fmaxf(acc.y + b1v[nt], 0.f);
            sAgg[(quad*4+2)*68 + nt*16+col] = fmaxf(acc.z + b1v[nt], 0.f);
            sAgg[(quad*4+3)*68 + nt*16+col] = fmaxf(acc.w + b1v[nt], 0.f);
        }
        const float* hr = &sAgg[col*68 + quad*8];
        float4 q0 = *(const float4*)&hr[0];
        float4 q1 = *(const float4*)&hr[4];
        float4 q2 = *(const float4*)&hr[32];
        float4 q3 = *(const float4*)&hr[36];
        F8 e0, e1;
        e0.u[0] = pk2h(q0.x, q0.y); e0.u[1] = pk2h(q0.z, q0.w);
        e0.u[2] = pk2h(q1.x, q1.y); e0.u[3] = pk2h(q1.z, q1.w);
        e1.u[0] = pk2h(q2.x, q2.y); e1.u[1] = pk2h(q2.z, q2.w);
        e1.u[2] = pk2h(q3.x, q3.y); e1.u[3] = pk2h(q3.z, q3.w);
        float ss[4], sq[4];
        #pragma unroll
        for (int nt = 0; nt < 4; nt++) {
            f32x4 acc = {0.f,0.f,0.f,0.f};
            F8 bf; bf.v = *(const f16x8*)&sW2u[(((0*4+nt)*4+quad)*16+col)*8];
            acc = __builtin_amdgcn_mfma_f32_16x16x32_f16(e0.v, bf.v, acc, 0, 0, 0);
            bf.v = *(const f16x8*)&sW2u[(((1*4+nt)*4+quad)*16+col)*8];
            acc = __builtin_amdgcn_mfma_f32_16x16x32_f16(e1.v, bf.v, acc, 0, 0, 0);
            float o0 = fmaxf(acc.x + b2v[nt], 0.f);
            float o1 = fmaxf(acc.y + b2v[nt], 0.f);
            float o2 = fmaxf(acc.z + b2v[nt], 0.f);
            float o3 = fmaxf(acc.w + b2v[nt], 0.f);
            h[(size_t)(n0w + quad*4 + 0)*64 + nt*16 + col] = o0;
            h[(size_t)(n0w + quad*4 + 1)*64 + nt*16 + col] = o1;
            h[(size_t)(n0w + quad*4 + 2)*64 + nt*16 + col] = o2;
            h[(size_t)(n0w + quad*4 + 3)*64 + nt*16 + col] = o3;
            ss[nt] = (o0 + o1) + (o2 + o3);
            sq[nt] = (o0*o0 + o1*o1) + (o2*o2 + o3*o3);
        }
        #pragma unroll
        for (int nt = 0; nt < 4; nt++) {
            float v = ss[nt];
            v += __shfl_down(v, 32, 64); v += __shfl_down(v, 16, 64);
            ss[nt] = v;
            float w2 = sq[nt];
            w2 += __shfl_down(w2, 32, 64); w2 += __shfl_down(w2, 16, 64);
            sq[nt] = w2;
        }
        if (lane < 16) {
            int b = (int)(blockIdx.x >> 7);
            #pragma unroll
            for (int nt = 0; nt < 4; nt++) {
                atomicAdd(&gout[b*64 + nt*16 + lane], ss[nt]);
                atomicAdd(&gout[NB*64 + b*64 + nt*16 + lane], sq[nt]);
            }
        }
    }
}

// MFMA pre (layers 1,2): normalize h (write back), A = h@W1a+b1 (f16), B = h@W1b (f16); zero gz.
__global__ __launch_bounds__(256) void k_preM(
    float* __restrict__ h,
    const float* __restrict__ W1, const float* __restrict__ B1,
    _Float16* __restrict__ A, _Float16* __restrict__ Bm,
    const float* __restrict__ gin, float* __restrict__ gz)
{
    alignas(16) __shared__ _Float16 sWp[8192];   // [ks2][nt8][qd4][col16][j8]
    __shared__ float sMean[64], sRstd[64];
    for (int idx = threadIdx.x; idx < 8192; idx += 256) {
        int k = idx >> 7, n = idx & 127;
        float val = (n < 64) ? W1[k*64 + n] : W1[(64+k)*64 + (n-64)];
        int ks = k >> 5, qd = (k >> 3) & 3, j = k & 7, nt = n >> 4, cl = n & 15;
        sWp[(((ks*8+nt)*4+qd)*16+cl)*8 + j] = (_Float16)val;
    }
    if (threadIdx.x < 64) {
        int b = (int)(blockIdx.x >> 5);
        float s  = gin[b*64 + threadIdx.x];
        float qq = gin[NB*64 + b*64 + threadIdx.x];
        float mean = s * (1.f/NS);
        float var  = qq * (1.f/NS) - mean*mean;
        sMean[threadIdx.x] = mean;
        sRstd[threadIdx.x] = rsqrtf(var + EPSF);
    }
    if (blockIdx.x == 0)
        for (int i = threadIdx.x; i < 2*NB*64; i += 256) gz[i] = 0.f;
    __syncthreads();
    const int lane = threadIdx.x & 63;
    const int wv = threadIdx.x >> 6;
    const int col = lane & 15, quad = lane >> 4;
    const int n0w = blockIdx.x*64 + wv*16;
    float* hp = &h[(size_t)(n0w+col)*64 + quad*8];
    float xv[16];
    *(float4*)&xv[0]  = *(const float4*)&hp[0];
    *(float4*)&xv[4]  = *(const float4*)&hp[4];
    *(float4*)&xv[8]  = *(const float4*)&hp[32];
    *(float4*)&xv[12] = *(const float4*)&hp[36];
    #pragma unroll
    for (int t2 = 0; t2 < 8; t2++) {
        int f = quad*8 + t2;
        xv[t2] = (xv[t2] - sMean[f]) * sRstd[f];
    }
    #pragma unroll
    for (int t2 = 0; t2 < 8; t2++) {
        int f = 32 + quad*8 + t2;
        xv[8+t2] = (xv[8+t2] - sMean[f]) * sRstd[f];
    }
    *(float4*)&hp[0]  = *(float4*)&xv[0];
    *(float4*)&hp[4]  = *(float4*)&xv[4];
    *(float4*)&hp[32] = *(float4*)&xv[8];
    *(float4*)&hp[36] = *(float4*)&xv[12];
    F8 af0, af1;
    af0.u[0] = pk2h(xv[0],  xv[1]);  af0.u[1] = pk2h(xv[2],  xv[3]);
    af0.u[2] = pk2h(xv[4],  xv[5]);  af0.u[3] = pk2h(xv[6],  xv[7]);
    af1.u[0] = pk2h(xv[8],  xv[9]);  af1.u[1] = pk2h(xv[10], xv[11]);
    af1.u[2] = pk2h(xv[12], xv[13]); af1.u[3] = pk2h(xv[14], xv[15]);
    float b1v[4];
    #pragma unroll
    for (int nt = 0; nt < 4; nt++) b1v[nt] = B1[nt*16+col];
    #pragma unroll
    for (int nt = 0; nt < 8; nt++) {
        f32x4 acc = {0.f,0.f,0.f,0.f};
        F8 bf; bf.v = *(const f16x8*)&sWp[(((0*8+nt)*4+quad)*16+col)*8];
        acc = __builtin_amdgcn_mfma_f32_16x16x32_f16(af0.v, bf.v, acc, 0, 0, 0);
        bf.v = *(const f16x8*)&sWp[(((1*8+nt)*4+quad)*16+col)*8];
        acc = __builtin_amdgcn_mfma_f32_16x16x32_f16(af1.v, bf.v, acc, 0, 0, 0);
        if (nt < 4) {
            float bb = b1v[nt];
            A[(size_t)(n0w + quad*4 + 0)*64 + nt*16 + col] = (_Float16)(acc.x + bb);
            A[(size_t)(n0w + quad*4 + 1)*64 + nt*16 + col] = (_Float16)(acc.y + bb);
            A[(size_t)(n0w + quad*4 + 2)*64 + nt*16 + col] = (_Float16)(acc.z + bb);
            A[(size_t)(n0w + quad*4 + 3)*64 + nt*16 + col] = (_Float16)(acc.w + bb);
        } else {
            Bm[(size_t)(n0w + quad*4 + 0)*64 + (nt-4)*16 + col] = (_Float16)acc.x;
            Bm[(size_t)(n0w + quad*4 + 1)*64 + (nt-4)*16 + col] = (_Float16)acc.y;
            Bm[(size_t)(n0w + quad*4 + 2)*64 + (nt-4)*16 + col] = (_Float16)acc.z;
            Bm[(size_t)(n0w + quad*4 + 3)*64 + (nt-4)*16 + col] = (_Float16)acc.w;
        }
    }
}

// Fused: instance-norm + decode + sigmoid + t2-term reduction (round-9 layout)
__global__ __launch_bounds__(256) void k_dec(
    const float* __restrict__ h, const float* __restrict__ Wd, const float* __restrict__ bd,
    const float* __restrict__ g, float* __restrict__ xbuf, float* __restrict__ out1,
    float* __restrict__ accum)
{
    int n = blockIdx.x*256 + threadIdx.x;
    int b = n >> 11;
    __shared__ float sM[64], sR[64];
    __shared__ float sWd[256];
    if (threadIdx.x < 64) {
        float s  = g[b*64 + threadIdx.x];
        float qq = g[NB*64 + b*64 + threadIdx.x];
        float mean = s * (1.f/NS);
        float var  = qq * (1.f/NS) - mean*mean;
        sM[threadIdx.x] = mean; sR[threadIdx.x] = rsqrtf(var + EPSF);
    }
    for (int i = threadIdx.x; i < 256; i += 256) sWd[i] = Wd[i];
    __syncthreads();
    float a0 = bd[0], a1 = bd[1], a2 = bd[2], a3 = bd[3];
    const float* hr = h + (size_t)n*64;
    #pragma unroll 8
    for (int k = 0; k < 64; k++) {
        float v = (hr[k] - sM[k]) * sR[k];
        a0 = fmaf(v, sWd[k*4+0], a0);
        a1 = fmaf(v, sWd[k*4+1], a1);
        a2 = fmaf(v, sWd[k*4+2], a2);
        a3 = fmaf(v, sWd[k*4+3], a3);
    }
    float4 o;
    o.x = 1.f/(1.f + expf(-a0));
    o.y = 1.f/(1.f + expf(-a1));
    o.z = 1.f/(1.f + expf(-a2));
    o.w = 1.f/(1.f + expf(-a3));
    *(float4*)&xbuf[(size_t)n*4] = o;
    out1[n*4+0] = o.x; out1[n*4+1] = o.y; out1[n*4+2] = o.z; out1[n*4+3] = o.w;
    float p = (1.f-o.x*o.x)*(1.f-o.y*o.y)*(1.f-o.z*o.z)*(1.f-o.w*o.w);
    for (int offs = 32; offs; offs >>= 1) p += __shfl_down(p, offs, 64);
    __shared__ float ws[4];
    if ((threadIdx.x & 63) == 0) ws[threadIdx.x >> 6] = p;
    __syncthreads();
    if (threadIdx.x == 0) atomicAdd(&accum[0], ws[0]+ws[1]+ws[2]+ws[3]);
}

// t3 pairwise term + final loss via last-block ticket (round-9 layout: 256 blocks)
__global__ __launch_bounds__(256) void k_t3(const float* __restrict__ X,
                                            float* __restrict__ accum,
                                            float* __restrict__ out)
{
    int b = blockIdx.x >> 5, c = blockIdx.x & 31;
    __shared__ float sX[NS*4];
    const float* Xb = X + (size_t)b*NS*4;
    for (int idx = threadIdx.x; idx < NS*4; idx += 256) sX[idx] = Xb[idx];
    __syncthreads();
    const float4* sX4 = (const float4*)sX;
    int il = threadIdx.x & 63, wv = threadIdx.x >> 6;
    float4 xi = sX4[c*64 + il];
    float acc = 0.f;
    #pragma unroll 4
    for (int s = 0; s < 512; s++) {
        float4 xj = sX4[wv*512 + s];
        acc += (1.f - fmaxf(xi.x, xj.x)) * (1.f - fmaxf(xi.y, xj.y))
             * (1.f - fmaxf(xi.z, xj.z)) * (1.f - fmaxf(xi.w, xj.w));
    }
    for (int offs = 32; offs; offs >>= 1) acc += __shfl_down(acc, offs, 64);
    __shared__ float ws[4];
    if (il == 0) ws[wv] = acc;
    __syncthreads();
    if (threadIdx.x == 0) {
        atomicAdd(&accum[1], ws[0]+ws[1]+ws[2]+ws[3]);
        __threadfence();
        unsigned t = atomicAdd((unsigned int*)&accum[2], 1u);
        if (t == (unsigned)(NB*32 - 1)) {
            float A2 = __hip_atomic_load(&accum[0], __ATOMIC_ACQUIRE, __HIP_MEMORY_SCOPE_AGENT);
            float A3 = __hip_atomic_load(&accum[1], __ATOMIC_ACQUIRE, __HIP_MEMORY_SCOPE_AGENT);
            float t1 = 1.f/81.f;
            float t2 = (2.f/(NS*16.f)) * (A2 / NB);
            float t3 = (A3 / ((float)NS*(float)NS)) / NB;
            out[0] = t1 - t2 + t3;
        }
    }
}

extern "C" void kernel_launch(void* const* d_in, const int* in_sizes, int n_in,
                              void* d_out, int out_size, void* d_ws, size_t ws_size,
                              hipStream_t stream)
{
    const float* x     = (const float*)d_in[0];
    const int*   ei    = (const int*)d_in[1];
    const float* enc_w = (const float*)d_in[2];
    const float* enc_b = (const float*)d_in[3];
    const float* m1w   = (const float*)d_in[4];
    const float* m1b   = (const float*)d_in[5];
    const float* m2w   = (const float*)d_in[6];
    const float* m2b   = (const float*)d_in[7];
    const float* u1w   = (const float*)d_in[8];
    const float* u1b   = (const float*)d_in[9];
    const float* u2w   = (const float*)d_in[10];
    const float* u2b   = (const float*)d_in[11];
    const float* dw    = (const float*)d_in[12];
    const float* db    = (const float*)d_in[13];
    float* out = (float*)d_out;

    float*    h   = (float*)d_ws;              // NN*64 f32
    _Float16* Ah  = (_Float16*)(h + NN*64);    // NN*64 f16
    _Float16* Bh  = Ah + NN*64;                // NN*64 f16
    float*    g0  = (float*)(Bh + NN*64);      // 2*NB*64
    float*    g1  = g0 + 2*NB*64;              // 2*NB*64
    float*    acc = g1 + 2*NB*64;              // 4
    int*      deg = (int*)(acc + 4);           // NN
    int*      ssrc= deg + NN;                  // NN*64
    float*    xbuf= (float*)Ah;                // alias (Ah dead after last eu)

    const int* srcv = ei;
    const int* tgtv = ei + NE;
    float* gbuf[2] = {g0, g1};

    k_init<<<NN/256, 256, 0, stream>>>(deg, acc);
    k_pre0M<<<NN/64, 256, 0, stream>>>(x, enc_w, enc_b, h, m1w, m1b,
                                       Ah, Bh, g0, srcv, tgtv, deg, ssrc);

    for (int l = 0; l < 3; l++) {
        if (l)
            k_preM<<<NN/64, 256, 0, stream>>>(h, m1w + l*128*64, m1b + l*64,
                                              Ah, Bh,
                                              gbuf[(l+1)&1], gbuf[l&1]);
        k_eu<<<NN/16, 256, 0, stream>>>(Ah, Bh, deg, ssrc,
                                        m2w + l*64*64, m2b + l*64,
                                        h,
                                        u1w + l*128*64, u1b + l*64,
                                        u2w + l*64*64,  u2b + l*64,
                                        gbuf[l&1]);
    }

    k_dec<<<NN/256, 256, 0, stream>>>(h, dw, db, g0, xbuf, out + 1, acc);
    k_t3<<<NB*32, 256, 0, stream>>>(xbuf, acc, out);
}

// Round 13
// 206.103 us; speedup vs baseline: 1.2189x; 1.0745x over previous
//
#include <hip/hip_runtime.h>
#include <hip/hip_fp16.h>
#include <math.h>

#define NB 8
#define NS 2048
#define NN (NB*NS)       // 16384 nodes
#define NE (NN*16)       // 262144 edges
#define EPSF 1e-5f

typedef float  f32x4 __attribute__((ext_vector_type(4)));
typedef _Float16 f16x8 __attribute__((ext_vector_type(8)));
union F8 { f16x8 v; unsigned u[4]; };

__device__ __forceinline__ unsigned pk2h(float a, float b) {
    __half2 hh = __floats2half2_rn(a, b);
    unsigned u; __builtin_memcpy(&u, &hh, 4); return u;
}

__device__ __forceinline__ f16x8 relu8(f16x8 v) {
    #pragma unroll
    for (int i = 0; i < 8; i++) v[i] = v[i] > (_Float16)0.f ? v[i] : (_Float16)0.f;
    return v;
}

// zero deg (NN) and acc (4)
__global__ __launch_bounds__(256) void k_init(int* __restrict__ deg,
                                              float* __restrict__ acc)
{
    int i = blockIdx.x*256 + threadIdx.x;
    if (i < NN) deg[i] = 0;
    if (i < 4) acc[i] = 0.f;
}

// Layer 0 (MFMA): slotted-CSR scatter; enc -> h; A = h@W1a+b1 (f16); Bm = h@W1b (f16); zero g0.
__global__ __launch_bounds__(256) void k_pre0M(
    const float* __restrict__ x,
    const float* __restrict__ encW, const float* __restrict__ encB,
    float* __restrict__ h,
    const float* __restrict__ W1, const float* __restrict__ B1,
    _Float16* __restrict__ A, _Float16* __restrict__ Bm,
    float* __restrict__ gz,
    const int* __restrict__ srcv, const int* __restrict__ tgtv,
    int* __restrict__ deg, int* __restrict__ ssrc)
{
    alignas(16) __shared__ _Float16 sWp[8192];   // [ks2][nt8][qd4][col16][j8]
    __shared__ float sEw[256], sEb[64];
    {   // slotted-CSR scatter: 4 edges per thread (256 blocks x 256 thr)
        int gid = blockIdx.x*256 + threadIdx.x;
        #pragma unroll
        for (int it = 0; it < 4; it++) {
            int e = gid + it*65536;
            int t = tgtv[e];
            int pos = atomicAdd(&deg[t], 1) & 63;
            ssrc[t*64 + pos] = srcv[e];
        }
    }
    // vectorized staging: unit = (kgroup of 8 k, n); 8 coalesced loads -> 1 ds_write_b128
    for (int it = threadIdx.x; it < 1024; it += 256) {
        int kg = it >> 7, n = it & 127;
        int nt = n >> 4, cl = n & 15;
        int ks = kg >> 2, qd = kg & 3;
        F8 tmp;
        #pragma unroll
        for (int j = 0; j < 8; j++) {
            int k = kg*8 + j;
            float val = (n < 64) ? W1[k*64 + n] : W1[(64+k)*64 + (n-64)];
            tmp.v[j] = (_Float16)val;
        }
        *(f16x8*)&sWp[(((ks*8+nt)*4+qd)*16+cl)*8] = tmp.v;
    }
    sEw[threadIdx.x] = encW[threadIdx.x];
    if (threadIdx.x < 64) sEb[threadIdx.x] = encB[threadIdx.x];
    if (blockIdx.x == 0)
        for (int i = threadIdx.x; i < 2*NB*64; i += 256) gz[i] = 0.f;
    __syncthreads();
    const int lane = threadIdx.x & 63;
    const int wv = threadIdx.x >> 6;
    const int col = lane & 15, quad = lane >> 4;
    const int n0w = blockIdx.x*64 + wv*16;
    const int n = n0w + col;
    float4 x4 = *(const float4*)&x[(size_t)n*4];
    float xv[16];
    #pragma unroll
    for (int hh = 0; hh < 2; hh++)
        #pragma unroll
        for (int j = 0; j < 8; j++) {
            int f = hh*32 + quad*8 + j;
            float v = sEb[f];
            v = fmaf(x4.x, sEw[f],     v);
            v = fmaf(x4.y, sEw[64+f],  v);
            v = fmaf(x4.z, sEw[128+f], v);
            v = fmaf(x4.w, sEw[192+f], v);
            xv[hh*8+j] = v;
        }
    float* hp = &h[(size_t)n*64 + quad*8];
    *(float4*)&hp[0]  = *(float4*)&xv[0];
    *(float4*)&hp[4]  = *(float4*)&xv[4];
    *(float4*)&hp[32] = *(float4*)&xv[8];
    *(float4*)&hp[36] = *(float4*)&xv[12];
    F8 af0, af1;
    af0.u[0] = pk2h(xv[0],  xv[1]);  af0.u[1] = pk2h(xv[2],  xv[3]);
    af0.u[2] = pk2h(xv[4],  xv[5]);  af0.u[3] = pk2h(xv[6],  xv[7]);
    af1.u[0] = pk2h(xv[8],  xv[9]);  af1.u[1] = pk2h(xv[10], xv[11]);
    af1.u[2] = pk2h(xv[12], xv[13]); af1.u[3] = pk2h(xv[14], xv[15]);
    float b1v[4];
    #pragma unroll
    for (int nt = 0; nt < 4; nt++) b1v[nt] = B1[nt*16+col];
    #pragma unroll
    for (int nt = 0; nt < 8; nt++) {
        f32x4 acc = {0.f,0.f,0.f,0.f};
        F8 bf; bf.v = *(const f16x8*)&sWp[(((0*8+nt)*4+quad)*16+col)*8];
        acc = __builtin_amdgcn_mfma_f32_16x16x32_f16(af0.v, bf.v, acc, 0, 0, 0);
        bf.v = *(const f16x8*)&sWp[(((1*8+nt)*4+quad)*16+col)*8];
        acc = __builtin_amdgcn_mfma_f32_16x16x32_f16(af1.v, bf.v, acc, 0, 0, 0);
        if (nt < 4) {
            float bb = b1v[nt];
            A[(size_t)(n0w + quad*4 + 0)*64 + nt*16 + col] = (_Float16)(acc.x + bb);
            A[(size_t)(n0w + quad*4 + 1)*64 + nt*16 + col] = (_Float16)(acc.y + bb);
            A[(size_t)(n0w + quad*4 + 2)*64 + nt*16 + col] = (_Float16)(acc.z + bb);
            A[(size_t)(n0w + quad*4 + 3)*64 + nt*16 + col] = (_Float16)(acc.w + bb);
        } else {
            Bm[(size_t)(n0w + quad*4 + 0)*64 + (nt-4)*16 + col] = (_Float16)acc.x;
            Bm[(size_t)(n0w + quad*4 + 1)*64 + (nt-4)*16 + col] = (_Float16)acc.y;
            Bm[(size_t)(n0w + quad*4 + 2)*64 + (nt-4)*16 + col] = (_Float16)acc.z;
            Bm[(size_t)(n0w + quad*4 + 3)*64 + (nt-4)*16 + col] = (_Float16)acc.w;
        }
    }
}

// Fused edge+update (round-9 structure): block = 16 targets; 4 waves x 4 targets
// edge MFMA -> LDS agg tile; wave 0 runs the 16-node update MLP from LDS.
__global__ __launch_bounds__(256, 4) void k_eu(
    const _Float16* __restrict__ A, const _Float16* __restrict__ Bm,
    const int* __restrict__ deg, const int* __restrict__ ssrc,
    const float* __restrict__ W2e, const float* __restrict__ B2e,
    float* __restrict__ h,
    const float* __restrict__ W1u, const float* __restrict__ B1u,
    const float* __restrict__ W2u, const float* __restrict__ B2u,
    float* __restrict__ gout)
{
    alignas(16) __shared__ _Float16 sW1u[8192];   // u1 packed
    alignas(16) __shared__ _Float16 sW2u[4096];   // u2 packed
    alignas(16) __shared__ _Float16 sM2[4096];    // m2 packed (edge W2)
    alignas(16) __shared__ float sAgg[16*68];     // agg tile, reused as hid tile
    // vectorized staging: W1u = 16 kgroups x 64 n; W2u/M2 = 8 kgroups x 64 n
    for (int it = threadIdx.x; it < 1024; it += 256) {
        int kg = it >> 6, n = it & 63;
        int nt = n >> 4, cl = n & 15;
        int ks = kg >> 2, qd = kg & 3;
        F8 tmp;
        #pragma unroll
        for (int j = 0; j < 8; j++) tmp.v[j] = (_Float16)W1u[(kg*8+j)*64 + n];
        *(f16x8*)&sW1u[(((ks*4+nt)*4+qd)*16+cl)*8] = tmp.v;
    }
    for (int it = threadIdx.x; it < 512; it += 256) {
        int kg = it >> 6, n = it & 63;
        int nt = n >> 4, cl = n & 15;
        int ks = kg >> 2, qd = kg & 3;
        F8 t1, t2;
        #pragma unroll
        for (int j = 0; j < 8; j++) {
            t1.v[j] = (_Float16)W2u[(kg*8+j)*64 + n];
            t2.v[j] = (_Float16)W2e[(kg*8+j)*64 + n];
        }
        *(f16x8*)&sW2u[(((ks*4+nt)*4+qd)*16+cl)*8] = t1.v;
        *(f16x8*)&sM2 [(((ks*4+nt)*4+qd)*16+cl)*8] = t2.v;
    }
    __syncthreads();
    const int lane = threadIdx.x & 63;
    const int wv = threadIdx.x >> 6;
    const int col = lane & 15, quad = lane >> 4;
    F8 bfe[4][2];
    #pragma unroll
    for (int nt = 0; nt < 4; nt++)
        #pragma unroll
        for (int ks = 0; ks < 2; ks++)
            bfe[nt][ks].v = *(const f16x8*)&sM2[(((ks*4+nt)*4+quad)*16+col)*8];
    float b2e[4];
    #pragma unroll
    for (int nt = 0; nt < 4; nt++) b2e[nt] = B2e[nt*16 + col];

    const int t_base = blockIdx.x * 16;
    int cnts[4], sv[4];
    #pragma unroll
    for (int m = 0; m < 4; m++) {
        int t = t_base + wv*4 + m;
        cnts[m] = deg[t];
        sv[m] = ssrc[t*64 + lane];
    }
    #pragma unroll
    for (int m = 0; m < 4; m++) {
        int t = t_base + wv*4 + m;
        int cnt = cnts[m] > 64 ? 64 : cnts[m];
        const _Float16* ar = &A[(size_t)t*64 + quad*8];
        f16x8 aLo = *(const f16x8*)&ar[0];
        f16x8 aHi = *(const f16x8*)&ar[32];
        float cs[4] = {0.f, 0.f, 0.f, 0.f};
        for (int s0 = 0; s0 < cnt; s0 += 16) {
            int v = cnt - s0;
            int cc = col < v-1 ? col : v-1;
            int sr = __shfl(sv[m], s0 + cc, 64);
            const _Float16* br = &Bm[(size_t)sr*64 + quad*8];
            f16x8 bLo = *(const f16x8*)&br[0];
            f16x8 bHi = *(const f16x8*)&br[32];
            F8 af0, af1;
            af0.v = relu8(aLo + bLo);
            af1.v = relu8(aHi + bHi);
            #pragma unroll
            for (int nt = 0; nt < 4; nt++) {
                f32x4 acc = __builtin_amdgcn_mfma_f32_16x16x32_f16(
                                af0.v, bfe[nt][0].v, (f32x4){0.f,0.f,0.f,0.f}, 0, 0, 0);
                acc = __builtin_amdgcn_mfma_f32_16x16x32_f16(
                                af1.v, bfe[nt][1].v, acc, 0, 0, 0);
                float r0 = (quad*4+0 < v) ? fmaxf(acc.x + b2e[nt], 0.f) : 0.f;
                float r1 = (quad*4+1 < v) ? fmaxf(acc.y + b2e[nt], 0.f) : 0.f;
                float r2 = (quad*4+2 < v) ? fmaxf(acc.z + b2e[nt], 0.f) : 0.f;
                float r3 = (quad*4+3 < v) ? fmaxf(acc.w + b2e[nt], 0.f) : 0.f;
                cs[nt] += (r0 + r1) + (r2 + r3);
            }
        }
        #pragma unroll
        for (int nt = 0; nt < 4; nt++) {
            float vv = cs[nt];
            vv += __shfl_down(vv, 32, 64);
            vv += __shfl_down(vv, 16, 64);
            cs[nt] = vv;
        }
        if (lane < 16) {
            sAgg[(wv*4+m)*68 +  0 + lane] = cs[0];
            sAgg[(wv*4+m)*68 + 16 + lane] = cs[1];
            sAgg[(wv*4+m)*68 + 32 + lane] = cs[2];
            sAgg[(wv*4+m)*68 + 48 + lane] = cs[3];
        }
    }
    __syncthreads();
    if (wv == 0) {
        const int n0w = t_base;
        const float* hp = &h[(size_t)(n0w+col)*64 + quad*8];
        float4 h0 = *(const float4*)&hp[0];
        float4 h1 = *(const float4*)&hp[4];
        float4 h2 = *(const float4*)&hp[32];
        float4 h3 = *(const float4*)&hp[36];
        const float* ap = &sAgg[col*68 + quad*8];
        float4 g0 = *(const float4*)&ap[0];
        float4 g1 = *(const float4*)&ap[4];
        float4 g2 = *(const float4*)&ap[32];
        float4 g3 = *(const float4*)&ap[36];
        F8 af[4];
        af[0].u[0] = pk2h(h0.x, h0.y); af[0].u[1] = pk2h(h0.z, h0.w);
        af[0].u[2] = pk2h(h1.x, h1.y); af[0].u[3] = pk2h(h1.z, h1.w);
        af[1].u[0] = pk2h(h2.x, h2.y); af[1].u[1] = pk2h(h2.z, h2.w);
        af[1].u[2] = pk2h(h3.x, h3.y); af[1].u[3] = pk2h(h3.z, h3.w);
        af[2].u[0] = pk2h(g0.x, g0.y); af[2].u[1] = pk2h(g0.z, g0.w);
        af[2].u[2] = pk2h(g1.x, g1.y); af[2].u[3] = pk2h(g1.z, g1.w);
        af[3].u[0] = pk2h(g2.x, g2.y); af[3].u[1] = pk2h(g2.z, g2.w);
        af[3].u[2] = pk2h(g3.x, g3.y); af[3].u[3] = pk2h(g3.z, g3.w);
        float b1v[4], b2v[4];
        #pragma unroll
        for (int nt = 0; nt < 4; nt++) { b1v[nt] = B1u[nt*16+col]; b2v[nt] = B2u[nt*16+col]; }
        #pragma unroll
        for (int nt = 0; nt < 4; nt++) {
            f32x4 acc = {0.f,0.f,0.f,0.f};
            #pragma unroll
            for (int ks = 0; ks < 4; ks++) {
                F8 bf; bf.v = *(const f16x8*)&sW1u[(((ks*4+nt)*4+quad)*16+col)*8];
                acc = __builtin_amdgcn_mfma_f32_16x16x32_f16(af[ks].v, bf.v, acc, 0, 0, 0);
            }
            sAgg[(quad*4+0)*68 + nt*16+col] = fmaxf(acc.x + b1v[nt], 0.f);
            sAgg[(quad*4+1)*68 + nt*16+col] = fmaxf(acc.y + b1v[nt], 0.f);
            sAgg[(quad*4+2)*68 + nt*16+col] = fmaxf(acc.z + b1v[nt], 0.f);
            sAgg[(quad*4+3)*68 + nt*16+col] = fmaxf(acc.w + b1v[nt], 0.f);
        }
        const float* hr = &sAgg[col*68 + quad*8];
        float4 q0 = *(const float4*)&hr[0];
        float4 q1 = *(const float4*)&hr[4];
        float4 q2 = *(const float4*)&hr[32];
        float4 q3 = *(const float4*)&hr[36];
        F8 e0, e1;
        e0.u[0] = pk2h(q0.x, q0.y); e0.u[1] = pk2h(q0.z, q0.w);
        e0.u[2] = pk2h(q1.x, q1.y); e0.u[3] = pk2h(q1.z, q1.w);
        e1.u[0] = pk2h(q2.x, q2.y); e1.u[1] = pk2h(q2.z, q2.w);
        e1.u[2] = pk2h(q3.x, q3.y); e1.u[3] = pk2h(q3.z, q3.w);
        float ss[4], sq[4];
        #pragma unroll
        for (int nt = 0; nt < 4; nt++) {
            f32x4 acc = {0.f,0.f,0.f,0.f};
            F8 bf; bf.v = *(const f16x8*)&sW2u[(((0*4+nt)*4+quad)*16+col)*8];
            acc = __builtin_amdgcn_mfma_f32_16x16x32_f16(e0.v, bf.v, acc, 0, 0, 0);
            bf.v = *(const f16x8*)&sW2u[(((1*4+nt)*4+quad)*16+col)*8];
            acc = __builtin_amdgcn_mfma_f32_16x16x32_f16(e1.v, bf.v, acc, 0, 0, 0);
            float o0 = fmaxf(acc.x + b2v[nt], 0.f);
            float o1 = fmaxf(acc.y + b2v[nt], 0.f);
            float o2 = fmaxf(acc.z + b2v[nt], 0.f);
            float o3 = fmaxf(acc.w + b2v[nt], 0.f);
            h[(size_t)(n0w + quad*4 + 0)*64 + nt*16 + col] = o0;
            h[(size_t)(n0w + quad*4 + 1)*64 + nt*16 + col] = o1;
            h[(size_t)(n0w + quad*4 + 2)*64 + nt*16 + col] = o2;
            h[(size_t)(n0w + quad*4 + 3)*64 + nt*16 + col] = o3;
            ss[nt] = (o0 + o1) + (o2 + o3);
            sq[nt] = (o0*o0 + o1*o1) + (o2*o2 + o3*o3);
        }
        #pragma unroll
        for (int nt = 0; nt < 4; nt++) {
            float v = ss[nt];
            v += __shfl_down(v, 32, 64); v += __shfl_down(v, 16, 64);
            ss[nt] = v;
            float w2 = sq[nt];
            w2 += __shfl_down(w2, 32, 64); w2 += __shfl_down(w2, 16, 64);
            sq[nt] = w2;
        }
        if (lane < 16) {
            int b = (int)(blockIdx.x >> 7);
            #pragma unroll
            for (int nt = 0; nt < 4; nt++) {
                atomicAdd(&gout[b*64 + nt*16 + lane], ss[nt]);
                atomicAdd(&gout[NB*64 + b*64 + nt*16 + lane], sq[nt]);
            }
        }
    }
}

// MFMA pre (layers 1,2): normalize h (write back), A/Bm (f16); zero gz.
__global__ __launch_bounds__(256) void k_preM(
    float* __restrict__ h,
    const float* __restrict__ W1, const float* __restrict__ B1,
    _Float16* __restrict__ A, _Float16* __restrict__ Bm,
    const float* __restrict__ gin, float* __restrict__ gz)
{
    alignas(16) __shared__ _Float16 sWp[8192];   // [ks2][nt8][qd4][col16][j8]
    __shared__ float sMean[64], sRstd[64];
    for (int it = threadIdx.x; it < 1024; it += 256) {
        int kg = it >> 7, n = it & 127;
        int nt = n >> 4, cl = n & 15;
        int ks = kg >> 2, qd = kg & 3;
        F8 tmp;
        #pragma unroll
        for (int j = 0; j < 8; j++) {
            int k = kg*8 + j;
            float val = (n < 64) ? W1[k*64 + n] : W1[(64+k)*64 + (n-64)];
            tmp.v[j] = (_Float16)val;
        }
        *(f16x8*)&sWp[(((ks*8+nt)*4+qd)*16+cl)*8] = tmp.v;
    }
    if (threadIdx.x < 64) {
        int b = (int)(blockIdx.x >> 5);
        float s  = gin[b*64 + threadIdx.x];
        float qq = gin[NB*64 + b*64 + threadIdx.x];
        float mean = s * (1.f/NS);
        float var  = qq * (1.f/NS) - mean*mean;
        sMean[threadIdx.x] = mean;
        sRstd[threadIdx.x] = rsqrtf(var + EPSF);
    }
    if (blockIdx.x == 0)
        for (int i = threadIdx.x; i < 2*NB*64; i += 256) gz[i] = 0.f;
    __syncthreads();
    const int lane = threadIdx.x & 63;
    const int wv = threadIdx.x >> 6;
    const int col = lane & 15, quad = lane >> 4;
    const int n0w = blockIdx.x*64 + wv*16;
    float* hp = &h[(size_t)(n0w+col)*64 + quad*8];
    float xv[16];
    *(float4*)&xv[0]  = *(const float4*)&hp[0];
    *(float4*)&xv[4]  = *(const float4*)&hp[4];
    *(float4*)&xv[8]  = *(const float4*)&hp[32];
    *(float4*)&xv[12] = *(const float4*)&hp[36];
    #pragma unroll
    for (int t2 = 0; t2 < 8; t2++) {
        int f = quad*8 + t2;
        xv[t2] = (xv[t2] - sMean[f]) * sRstd[f];
    }
    #pragma unroll
    for (int t2 = 0; t2 < 8; t2++) {
        int f = 32 + quad*8 + t2;
        xv[8+t2] = (xv[8+t2] - sMean[f]) * sRstd[f];
    }
    *(float4*)&hp[0]  = *(float4*)&xv[0];
    *(float4*)&hp[4]  = *(float4*)&xv[4];
    *(float4*)&hp[32] = *(float4*)&xv[8];
    *(float4*)&hp[36] = *(float4*)&xv[12];
    F8 af0, af1;
    af0.u[0] = pk2h(xv[0],  xv[1]);  af0.u[1] = pk2h(xv[2],  xv[3]);
    af0.u[2] = pk2h(xv[4],  xv[5]);  af0.u[3] = pk2h(xv[6],  xv[7]);
    af1.u[0] = pk2h(xv[8],  xv[9]);  af1.u[1] = pk2h(xv[10], xv[11]);
    af1.u[2] = pk2h(xv[12], xv[13]); af1.u[3] = pk2h(xv[14], xv[15]);
    float b1v[4];
    #pragma unroll
    for (int nt = 0; nt < 4; nt++) b1v[nt] = B1[nt*16+col];
    #pragma unroll
    for (int nt = 0; nt < 8; nt++) {
        f32x4 acc = {0.f,0.f,0.f,0.f};
        F8 bf; bf.v = *(const f16x8*)&sWp[(((0*8+nt)*4+quad)*16+col)*8];
        acc = __builtin_amdgcn_mfma_f32_16x16x32_f16(af0.v, bf.v, acc, 0, 0, 0);
        bf.v = *(const f16x8*)&sWp[(((1*8+nt)*4+quad)*16+col)*8];
        acc = __builtin_amdgcn_mfma_f32_16x16x32_f16(af1.v, bf.v, acc, 0, 0, 0);
        if (nt < 4) {
            float bb = b1v[nt];
            A[(size_t)(n0w + quad*4 + 0)*64 + nt*16 + col] = (_Float16)(acc.x + bb);
            A[(size_t)(n0w + quad*4 + 1)*64 + nt*16 + col] = (_Float16)(acc.y + bb);
            A[(size_t)(n0w + quad*4 + 2)*64 + nt*16 + col] = (_Float16)(acc.z + bb);
            A[(size_t)(n0w + quad*4 + 3)*64 + nt*16 + col] = (_Float16)(acc.w + bb);
        } else {
            Bm[(size_t)(n0w + quad*4 + 0)*64 + (nt-4)*16 + col] = (_Float16)acc.x;
            Bm[(size_t)(n0w + quad*4 + 1)*64 + (nt-4)*16 + col] = (_Float16)acc.y;
            Bm[(size_t)(n0w + quad*4 + 2)*64 + (nt-4)*16 + col] = (_Float16)acc.z;
            Bm[(size_t)(n0w + quad*4 + 3)*64 + (nt-4)*16 + col] = (_Float16)acc.w;
        }
    }
}

// Fused: instance-norm + decode + sigmoid + t2-term reduction
__global__ __launch_bounds__(256) void k_dec(
    const float* __restrict__ h, const float* __restrict__ Wd, const float* __restrict__ bd,
    const float* __restrict__ g, float* __restrict__ xbuf, float* __restrict__ out1,
    float* __restrict__ accum)
{
    int n = blockIdx.x*256 + threadIdx.x;
    int b = n >> 11;
    __shared__ float sM[64], sR[64];
    __shared__ float sWd[256];
    if (threadIdx.x < 64) {
        float s  = g[b*64 + threadIdx.x];
        float qq = g[NB*64 + b*64 + threadIdx.x];
        float mean = s * (1.f/NS);
        float var  = qq * (1.f/NS) - mean*mean;
        sM[threadIdx.x] = mean; sR[threadIdx.x] = rsqrtf(var + EPSF);
    }
    for (int i = threadIdx.x; i < 256; i += 256) sWd[i] = Wd[i];
    __syncthreads();
    float a0 = bd[0], a1 = bd[1], a2 = bd[2], a3 = bd[3];
    const float* hr = h + (size_t)n*64;
    #pragma unroll 8
    for (int k = 0; k < 64; k++) {
        float v = (hr[k] - sM[k]) * sR[k];
        a0 = fmaf(v, sWd[k*4+0], a0);
        a1 = fmaf(v, sWd[k*4+1], a1);
        a2 = fmaf(v, sWd[k*4+2], a2);
        a3 = fmaf(v, sWd[k*4+3], a3);
    }
    float4 o;
    o.x = 1.f/(1.f + expf(-a0));
    o.y = 1.f/(1.f + expf(-a1));
    o.z = 1.f/(1.f + expf(-a2));
    o.w = 1.f/(1.f + expf(-a3));
    *(float4*)&xbuf[(size_t)n*4] = o;
    out1[n*4+0] = o.x; out1[n*4+1] = o.y; out1[n*4+2] = o.z; out1[n*4+3] = o.w;
    float p = (1.f-o.x*o.x)*(1.f-o.y*o.y)*(1.f-o.z*o.z)*(1.f-o.w*o.w);
    for (int offs = 32; offs; offs >>= 1) p += __shfl_down(p, offs, 64);
    __shared__ float ws[4];
    if ((threadIdx.x & 63) == 0) ws[threadIdx.x >> 6] = p;
    __syncthreads();
    if (threadIdx.x == 0) atomicAdd(&accum[0], ws[0]+ws[1]+ws[2]+ws[3]);
}

// t3 pairwise term + final loss via last-block ticket
__global__ __launch_bounds__(256) void k_t3(const float* __restrict__ X,
                                            float* __restrict__ accum,
                                            float* __restrict__ out)
{
    int b = blockIdx.x >> 5, c = blockIdx.x & 31;
    __shared__ float sX[NS*4];
    const float* Xb = X + (size_t)b*NS*4;
    for (int idx = threadIdx.x; idx < NS*4; idx += 256) sX[idx] = Xb[idx];
    __syncthreads();
    const float4* sX4 = (const float4*)sX;
    int il = threadIdx.x & 63, wv = threadIdx.x >> 6;
    float4 xi = sX4[c*64 + il];
    float acc = 0.f;
    #pragma unroll 4
    for (int s = 0; s < 512; s++) {
        float4 xj = sX4[wv*512 + s];
        acc += (1.f - fmaxf(xi.x, xj.x)) * (1.f - fmaxf(xi.y, xj.y))
             * (1.f - fmaxf(xi.z, xj.z)) * (1.f - fmaxf(xi.w, xj.w));
    }
    for (int offs = 32; offs; offs >>= 1) acc += __shfl_down(acc, offs, 64);
    __shared__ float ws[4];
    if (il == 0) ws[wv] = acc;
    __syncthreads();
    if (threadIdx.x == 0) {
        atomicAdd(&accum[1], ws[0]+ws[1]+ws[2]+ws[3]);
        __threadfence();
        unsigned t = atomicAdd((unsigned int*)&accum[2], 1u);
        if (t == (unsigned)(NB*32 - 1)) {
            float A2 = __hip_atomic_load(&accum[0], __ATOMIC_ACQUIRE, __HIP_MEMORY_SCOPE_AGENT);
            float A3 = __hip_atomic_load(&accum[1], __ATOMIC_ACQUIRE, __HIP_MEMORY_SCOPE_AGENT);
            float t1 = 1.f/81.f;
            float t2 = (2.f/(NS*16.f)) * (A2 / NB);
            float t3 = (A3 / ((float)NS*(float)NS)) / NB;
            out[0] = t1 - t2 + t3;
        }
    }
}

extern "C" void kernel_launch(void* const* d_in, const int* in_sizes, int n_in,
                              void* d_out, int out_size, void* d_ws, size_t ws_size,
                              hipStream_t stream)
{
    const float* x     = (const float*)d_in[0];
    const int*   ei    = (const int*)d_in[1];
    const float* enc_w = (const float*)d_in[2];
    const float* enc_b = (const float*)d_in[3];
    const float* m1w   = (const float*)d_in[4];
    const float* m1b   = (const float*)d_in[5];
    const float* m2w   = (const float*)d_in[6];
    const float* m2b   = (const float*)d_in[7];
    const float* u1w   = (const float*)d_in[8];
    const float* u1b   = (const float*)d_in[9];
    const float* u2w   = (const float*)d_in[10];
    const float* u2b   = (const float*)d_in[11];
    const float* dw    = (const float*)d_in[12];
    const float* db    = (const float*)d_in[13];
    float* out = (float*)d_out;

    float*    h   = (float*)d_ws;              // NN*64 f32
    _Float16* Ah  = (_Float16*)(h + NN*64);    // NN*64 f16
    _Float16* Bh  = Ah + NN*64;                // NN*64 f16
    float*    g0  = (float*)(Bh + NN*64);      // 2*NB*64
    float*    g1  = g0 + 2*NB*64;              // 2*NB*64
    float*    acc = g1 + 2*NB*64;              // 4
    int*      deg = (int*)(acc + 4);           // NN
    int*      ssrc= deg + NN;                  // NN*64
    float*    xbuf= (float*)Ah;                // alias (Ah dead after last eu)

    const int* srcv = ei;
    const int* tgtv = ei + NE;
    float* gbuf[2] = {g0, g1};

    k_init<<<NN/256, 256, 0, stream>>>(deg, acc);
    k_pre0M<<<NN/64, 256, 0, stream>>>(x, enc_w, enc_b, h, m1w, m1b,
                                       Ah, Bh, g0, srcv, tgtv, deg, ssrc);

    for (int l = 0; l < 3; l++) {
        if (l)
            k_preM<<<NN/64, 256, 0, stream>>>(h, m1w + l*128*64, m1b + l*64,
                                              Ah, Bh,
                                              gbuf[(l+1)&1], gbuf[l&1]);
        k_eu<<<NN/16, 256, 0, stream>>>(Ah, Bh, deg, ssrc,
                                        m2w + l*64*64, m2b + l*64,
                                        h,
                                        u1w + l*128*64, u1b + l*64,
                                        u2w + l*64*64,  u2b + l*64,
                                        gbuf[l&1]);
    }

    k_dec<<<NN/256, 256, 0, stream>>>(h, dw, db, g0, xbuf, out + 1, acc);
    k_t3<<<NB*32, 256, 0, stream>>>(xbuf, acc, out);
}

// Round 14
// 202.844 us; speedup vs baseline: 1.2385x; 1.0161x over previous
//
#include <hip/hip_runtime.h>
#include <hip/hip_fp16.h>
#include <math.h>

#define NB 8
#define NS 2048
#define NN (NB*NS)       // 16384 nodes
#define NE (NN*16)       // 262144 edges
#define EPSF 1e-5f

typedef float  f32x4 __attribute__((ext_vector_type(4)));
typedef _Float16 f16x8 __attribute__((ext_vector_type(8)));
union F8 { f16x8 v; unsigned u[4]; };

__device__ __forceinline__ unsigned pk2h(float a, float b) {
    __half2 hh = __floats2half2_rn(a, b);
    unsigned u; __builtin_memcpy(&u, &hh, 4); return u;
}

__device__ __forceinline__ f16x8 relu8(f16x8 v) {
    #pragma unroll
    for (int i = 0; i < 8; i++) v[i] = v[i] > (_Float16)0.f ? v[i] : (_Float16)0.f;
    return v;
}

// zero deg (NN) + acc; pack all layer weights into f16 fragment images (once).
// pkM1 layout (preM/pre0M): [((ks*8+nt)*4+qd)*16+cl]*8+j over concat [W1a;W1b]
// pkU1/pkU2/pkM2 layout (eu): [((ks*4+nt)*4+qd)*16+cl]*8+j
__global__ __launch_bounds__(256) void k_init(
    int* __restrict__ deg, float* __restrict__ acc,
    const float* __restrict__ m1w, const float* __restrict__ u1w,
    const float* __restrict__ u2w, const float* __restrict__ m2w,
    _Float16* __restrict__ pkM1, _Float16* __restrict__ pkU1,
    _Float16* __restrict__ pkU2, _Float16* __restrict__ pkM2)
{
    int gid = blockIdx.x*256 + threadIdx.x;   // 64 blocks x 256 = 16384
    deg[gid] = 0;
    if (gid < 4) acc[gid] = 0.f;
    if (gid < 3072) {               // m1: 3 layers x 1024 units
        int l = gid >> 10, it = gid & 1023;
        int kg = it >> 7, n = it & 127;
        int nt = n >> 4, cl = n & 15;
        int ks = kg >> 2, qd = kg & 3;
        const float* W1 = m1w + l*8192;
        F8 tmp;
        #pragma unroll
        for (int j = 0; j < 8; j++) {
            int k = kg*8 + j;
            float val = (n < 64) ? W1[k*64 + n] : W1[(64+k)*64 + (n-64)];
            tmp.v[j] = (_Float16)val;
        }
        *(f16x8*)&pkM1[l*8192 + (((ks*8+nt)*4+qd)*16+cl)*8] = tmp.v;
    } else if (gid < 6144) {        // u1: 3 layers x 1024 units
        int g2 = gid - 3072;
        int l = g2 >> 10, it = g2 & 1023;
        int kg = it >> 6, n = it & 63;
        int nt = n >> 4, cl = n & 15;
        int ks = kg >> 2, qd = kg & 3;
        const float* W = u1w + l*8192;
        F8 tmp;
        #pragma unroll
        for (int j = 0; j < 8; j++) tmp.v[j] = (_Float16)W[(kg*8+j)*64 + n];
        *(f16x8*)&pkU1[l*8192 + (((ks*4+nt)*4+qd)*16+cl)*8] = tmp.v;
    } else if (gid < 7680) {        // u2: 3 layers x 512 units
        int g2 = gid - 6144;
        int l = g2 >> 9, it = g2 & 511;
        int kg = it >> 6, n = it & 63;
        int nt = n >> 4, cl = n & 15;
        int ks = kg >> 2, qd = kg & 3;
        const float* W = u2w + l*4096;
        F8 tmp;
        #pragma unroll
        for (int j = 0; j < 8; j++) tmp.v[j] = (_Float16)W[(kg*8+j)*64 + n];
        *(f16x8*)&pkU2[l*4096 + (((ks*4+nt)*4+qd)*16+cl)*8] = tmp.v;
    } else if (gid < 9216) {        // m2: 3 layers x 512 units
        int g2 = gid - 7680;
        int l = g2 >> 9, it = g2 & 511;
        int kg = it >> 6, n = it & 63;
        int nt = n >> 4, cl = n & 15;
        int ks = kg >> 2, qd = kg & 3;
        const float* W = m2w + l*4096;
        F8 tmp;
        #pragma unroll
        for (int j = 0; j < 8; j++) tmp.v[j] = (_Float16)W[(kg*8+j)*64 + n];
        *(f16x8*)&pkM2[l*4096 + (((ks*4+nt)*4+qd)*16+cl)*8] = tmp.v;
    }
}

// Layer 0 (MFMA): slotted-CSR scatter; enc -> h; A/Bm (f16); zero g0.
__global__ __launch_bounds__(256) void k_pre0M(
    const float* __restrict__ x,
    const float* __restrict__ encW, const float* __restrict__ encB,
    float* __restrict__ h,
    const _Float16* __restrict__ pkW1, const float* __restrict__ B1,
    _Float16* __restrict__ A, _Float16* __restrict__ Bm,
    float* __restrict__ gz,
    const int* __restrict__ srcv, const int* __restrict__ tgtv,
    int* __restrict__ deg, int* __restrict__ ssrc)
{
    alignas(16) __shared__ _Float16 sWp[8192];
    __shared__ float sEw[256], sEb[64];
    {   // slotted-CSR scatter: 4 edges per thread
        int gid = blockIdx.x*256 + threadIdx.x;
        #pragma unroll
        for (int it = 0; it < 4; it++) {
            int e = gid + it*65536;
            int t = tgtv[e];
            int pos = atomicAdd(&deg[t], 1) & 63;
            ssrc[t*64 + pos] = srcv[e];
        }
    }
    {   // flat copy of pre-packed weights: 1024 float4
        const float4* s = (const float4*)pkW1;
        float4* d = (float4*)sWp;
        for (int i = threadIdx.x; i < 1024; i += 256) d[i] = s[i];
    }
    sEw[threadIdx.x] = encW[threadIdx.x];
    if (threadIdx.x < 64) sEb[threadIdx.x] = encB[threadIdx.x];
    if (blockIdx.x == 0)
        for (int i = threadIdx.x; i < 2*NB*64; i += 256) gz[i] = 0.f;
    __syncthreads();
    const int lane = threadIdx.x & 63;
    const int wv = threadIdx.x >> 6;
    const int col = lane & 15, quad = lane >> 4;
    const int n0w = blockIdx.x*64 + wv*16;
    const int n = n0w + col;
    float4 x4 = *(const float4*)&x[(size_t)n*4];
    float xv[16];
    #pragma unroll
    for (int hh = 0; hh < 2; hh++)
        #pragma unroll
        for (int j = 0; j < 8; j++) {
            int f = hh*32 + quad*8 + j;
            float v = sEb[f];
            v = fmaf(x4.x, sEw[f],     v);
            v = fmaf(x4.y, sEw[64+f],  v);
            v = fmaf(x4.z, sEw[128+f], v);
            v = fmaf(x4.w, sEw[192+f], v);
            xv[hh*8+j] = v;
        }
    float* hp = &h[(size_t)n*64 + quad*8];
    *(float4*)&hp[0]  = *(float4*)&xv[0];
    *(float4*)&hp[4]  = *(float4*)&xv[4];
    *(float4*)&hp[32] = *(float4*)&xv[8];
    *(float4*)&hp[36] = *(float4*)&xv[12];
    F8 af0, af1;
    af0.u[0] = pk2h(xv[0],  xv[1]);  af0.u[1] = pk2h(xv[2],  xv[3]);
    af0.u[2] = pk2h(xv[4],  xv[5]);  af0.u[3] = pk2h(xv[6],  xv[7]);
    af1.u[0] = pk2h(xv[8],  xv[9]);  af1.u[1] = pk2h(xv[10], xv[11]);
    af1.u[2] = pk2h(xv[12], xv[13]); af1.u[3] = pk2h(xv[14], xv[15]);
    float b1v[4];
    #pragma unroll
    for (int nt = 0; nt < 4; nt++) b1v[nt] = B1[nt*16+col];
    #pragma unroll
    for (int nt = 0; nt < 8; nt++) {
        f32x4 acc = {0.f,0.f,0.f,0.f};
        F8 bf; bf.v = *(const f16x8*)&sWp[(((0*8+nt)*4+quad)*16+col)*8];
        acc = __builtin_amdgcn_mfma_f32_16x16x32_f16(af0.v, bf.v, acc, 0, 0, 0);
        bf.v = *(const f16x8*)&sWp[(((1*8+nt)*4+quad)*16+col)*8];
        acc = __builtin_amdgcn_mfma_f32_16x16x32_f16(af1.v, bf.v, acc, 0, 0, 0);
        if (nt < 4) {
            float bb = b1v[nt];
            A[(size_t)(n0w + quad*4 + 0)*64 + nt*16 + col] = (_Float16)(acc.x + bb);
            A[(size_t)(n0w + quad*4 + 1)*64 + nt*16 + col] = (_Float16)(acc.y + bb);
            A[(size_t)(n0w + quad*4 + 2)*64 + nt*16 + col] = (_Float16)(acc.z + bb);
            A[(size_t)(n0w + quad*4 + 3)*64 + nt*16 + col] = (_Float16)(acc.w + bb);
        } else {
            Bm[(size_t)(n0w + quad*4 + 0)*64 + (nt-4)*16 + col] = (_Float16)acc.x;
            Bm[(size_t)(n0w + quad*4 + 1)*64 + (nt-4)*16 + col] = (_Float16)acc.y;
            Bm[(size_t)(n0w + quad*4 + 2)*64 + (nt-4)*16 + col] = (_Float16)acc.z;
            Bm[(size_t)(n0w + quad*4 + 3)*64 + (nt-4)*16 + col] = (_Float16)acc.w;
        }
    }
}

// Fused edge+update: staging is now a flat copy of pre-packed fragment images.
__global__ __launch_bounds__(256, 4) void k_eu(
    const _Float16* __restrict__ A, const _Float16* __restrict__ Bm,
    const int* __restrict__ deg, const int* __restrict__ ssrc,
    const _Float16* __restrict__ pkM2l, const float* __restrict__ B2e,
    float* __restrict__ h,
    const _Float16* __restrict__ pkU1l, const float* __restrict__ B1u,
    const _Float16* __restrict__ pkU2l, const float* __restrict__ B2u,
    float* __restrict__ gout)
{
    alignas(16) __shared__ _Float16 sW1u[8192];
    alignas(16) __shared__ _Float16 sW2u[4096];
    alignas(16) __shared__ _Float16 sM2[4096];
    alignas(16) __shared__ float sAgg[16*68];
    {   // flat copies: 1024 + 512 + 512 float4
        const float4* s1 = (const float4*)pkU1l;
        float4* d1 = (float4*)sW1u;
        for (int i = threadIdx.x; i < 1024; i += 256) d1[i] = s1[i];
        const float4* s2 = (const float4*)pkU2l;
        const float4* s3 = (const float4*)pkM2l;
        float4* d2 = (float4*)sW2u;
        float4* d3 = (float4*)sM2;
        for (int i = threadIdx.x; i < 512; i += 256) { d2[i] = s2[i]; d3[i] = s3[i]; }
    }
    __syncthreads();
    const int lane = threadIdx.x & 63;
    const int wv = threadIdx.x >> 6;
    const int col = lane & 15, quad = lane >> 4;
    F8 bfe[4][2];
    #pragma unroll
    for (int nt = 0; nt < 4; nt++)
        #pragma unroll
        for (int ks = 0; ks < 2; ks++)
            bfe[nt][ks].v = *(const f16x8*)&sM2[(((ks*4+nt)*4+quad)*16+col)*8];
    float b2e[4];
    #pragma unroll
    for (int nt = 0; nt < 4; nt++) b2e[nt] = B2e[nt*16 + col];

    const int t_base = blockIdx.x * 16;
    int cnts[4], sv[4];
    #pragma unroll
    for (int m = 0; m < 4; m++) {
        int t = t_base + wv*4 + m;
        cnts[m] = deg[t];
        sv[m] = ssrc[t*64 + lane];
    }
    #pragma unroll
    for (int m = 0; m < 4; m++) {
        int t = t_base + wv*4 + m;
        int cnt = cnts[m] > 64 ? 64 : cnts[m];
        const _Float16* ar = &A[(size_t)t*64 + quad*8];
        f16x8 aLo = *(const f16x8*)&ar[0];
        f16x8 aHi = *(const f16x8*)&ar[32];
        float cs[4] = {0.f, 0.f, 0.f, 0.f};
        for (int s0 = 0; s0 < cnt; s0 += 16) {
            int v = cnt - s0;
            int cc = col < v-1 ? col : v-1;
            int sr = __shfl(sv[m], s0 + cc, 64);
            const _Float16* br = &Bm[(size_t)sr*64 + quad*8];
            f16x8 bLo = *(const f16x8*)&br[0];
            f16x8 bHi = *(const f16x8*)&br[32];
            F8 af0, af1;
            af0.v = relu8(aLo + bLo);
            af1.v = relu8(aHi + bHi);
            #pragma unroll
            for (int nt = 0; nt < 4; nt++) {
                f32x4 acc = __builtin_amdgcn_mfma_f32_16x16x32_f16(
                                af0.v, bfe[nt][0].v, (f32x4){0.f,0.f,0.f,0.f}, 0, 0, 0);
                acc = __builtin_amdgcn_mfma_f32_16x16x32_f16(
                                af1.v, bfe[nt][1].v, acc, 0, 0, 0);
                float r0 = (quad*4+0 < v) ? fmaxf(acc.x + b2e[nt], 0.f) : 0.f;
                float r1 = (quad*4+1 < v) ? fmaxf(acc.y + b2e[nt], 0.f) : 0.f;
                float r2 = (quad*4+2 < v) ? fmaxf(acc.z + b2e[nt], 0.f) : 0.f;
                float r3 = (quad*4+3 < v) ? fmaxf(acc.w + b2e[nt], 0.f) : 0.f;
                cs[nt] += (r0 + r1) + (r2 + r3);
            }
        }
        #pragma unroll
        for (int nt = 0; nt < 4; nt++) {
            float vv = cs[nt];
            vv += __shfl_down(vv, 32, 64);
            vv += __shfl_down(vv, 16, 64);
            cs[nt] = vv;
        }
        if (lane < 16) {
            sAgg[(wv*4+m)*68 +  0 + lane] = cs[0];
            sAgg[(wv*4+m)*68 + 16 + lane] = cs[1];
            sAgg[(wv*4+m)*68 + 32 + lane] = cs[2];
            sAgg[(wv*4+m)*68 + 48 + lane] = cs[3];
        }
    }
    __syncthreads();
    if (wv == 0) {
        const int n0w = t_base;
        const float* hp = &h[(size_t)(n0w+col)*64 + quad*8];
        float4 h0 = *(const float4*)&hp[0];
        float4 h1 = *(const float4*)&hp[4];
        float4 h2 = *(const float4*)&hp[32];
        float4 h3 = *(const float4*)&hp[36];
        const float* ap = &sAgg[col*68 + quad*8];
        float4 g0 = *(const float4*)&ap[0];
        float4 g1 = *(const float4*)&ap[4];
        float4 g2 = *(const float4*)&ap[32];
        float4 g3 = *(const float4*)&ap[36];
        F8 af[4];
        af[0].u[0] = pk2h(h0.x, h0.y); af[0].u[1] = pk2h(h0.z, h0.w);
        af[0].u[2] = pk2h(h1.x, h1.y); af[0].u[3] = pk2h(h1.z, h1.w);
        af[1].u[0] = pk2h(h2.x, h2.y); af[1].u[1] = pk2h(h2.z, h2.w);
        af[1].u[2] = pk2h(h3.x, h3.y); af[1].u[3] = pk2h(h3.z, h3.w);
        af[2].u[0] = pk2h(g0.x, g0.y); af[2].u[1] = pk2h(g0.z, g0.w);
        af[2].u[2] = pk2h(g1.x, g1.y); af[2].u[3] = pk2h(g1.z, g1.w);
        af[3].u[0] = pk2h(g2.x, g2.y); af[3].u[1] = pk2h(g2.z, g2.w);
        af[3].u[2] = pk2h(g3.x, g3.y); af[3].u[3] = pk2h(g3.z, g3.w);
        float b1v[4], b2v[4];
        #pragma unroll
        for (int nt = 0; nt < 4; nt++) { b1v[nt] = B1u[nt*16+col]; b2v[nt] = B2u[nt*16+col]; }
        #pragma unroll
        for (int nt = 0; nt < 4; nt++) {
            f32x4 acc = {0.f,0.f,0.f,0.f};
            #pragma unroll
            for (int ks = 0; ks < 4; ks++) {
                F8 bf; bf.v = *(const f16x8*)&sW1u[(((ks*4+nt)*4+quad)*16+col)*8];
                acc = __builtin_amdgcn_mfma_f32_16x16x32_f16(af[ks].v, bf.v, acc, 0, 0, 0);
            }
            sAgg[(quad*4+0)*68 + nt*16+col] = fmaxf(acc.x + b1v[nt], 0.f);
            sAgg[(quad*4+1)*68 + nt*16+col] = fmaxf(acc.y + b1v[nt], 0.f);
            sAgg[(quad*4+2)*68 + nt*16+col] = fmaxf(acc.z + b1v[nt], 0.f);
            sAgg[(quad*4+3)*68 + nt*16+col] = fmaxf(acc.w + b1v[nt], 0.f);
        }
        const float* hr = &sAgg[col*68 + quad*8];
        float4 q0 = *(const float4*)&hr[0];
        float4 q1 = *(const float4*)&hr[4];
        float4 q2 = *(const float4*)&hr[32];
        float4 q3 = *(const float4*)&hr[36];
        F8 e0, e1;
        e0.u[0] = pk2h(q0.x, q0.y); e0.u[1] = pk2h(q0.z, q0.w);
        e0.u[2] = pk2h(q1.x, q1.y); e0.u[3] = pk2h(q1.z, q1.w);
        e1.u[0] = pk2h(q2.x, q2.y); e1.u[1] = pk2h(q2.z, q2.w);
        e1.u[2] = pk2h(q3.x, q3.y); e1.u[3] = pk2h(q3.z, q3.w);
        float ss[4], sq[4];
        #pragma unroll
        for (int nt = 0; nt < 4; nt++) {
            f32x4 acc = {0.f,0.f,0.f,0.f};
            F8 bf; bf.v = *(const f16x8*)&sW2u[(((0*4+nt)*4+quad)*16+col)*8];
            acc = __builtin_amdgcn_mfma_f32_16x16x32_f16(e0.v, bf.v, acc, 0, 0, 0);
            bf.v = *(const f16x8*)&sW2u[(((1*4+nt)*4+quad)*16+col)*8];
            acc = __builtin_amdgcn_mfma_f32_16x16x32_f16(e1.v, bf.v, acc, 0, 0, 0);
            float o0 = fmaxf(acc.x + b2v[nt], 0.f);
            float o1 = fmaxf(acc.y + b2v[nt], 0.f);
            float o2 = fmaxf(acc.z + b2v[nt], 0.f);
            float o3 = fmaxf(acc.w + b2v[nt], 0.f);
            h[(size_t)(n0w + quad*4 + 0)*64 + nt*16 + col] = o0;
            h[(size_t)(n0w + quad*4 + 1)*64 + nt*16 + col] = o1;
            h[(size_t)(n0w + quad*4 + 2)*64 + nt*16 + col] = o2;
            h[(size_t)(n0w + quad*4 + 3)*64 + nt*16 + col] = o3;
            ss[nt] = (o0 + o1) + (o2 + o3);
            sq[nt] = (o0*o0 + o1*o1) + (o2*o2 + o3*o3);
        }
        #pragma unroll
        for (int nt = 0; nt < 4; nt++) {
            float v = ss[nt];
            v += __shfl_down(v, 32, 64); v += __shfl_down(v, 16, 64);
            ss[nt] = v;
            float w2 = sq[nt];
            w2 += __shfl_down(w2, 32, 64); w2 += __shfl_down(w2, 16, 64);
            sq[nt] = w2;
        }
        if (lane < 16) {
            int b = (int)(blockIdx.x >> 7);
            #pragma unroll
            for (int nt = 0; nt < 4; nt++) {
                atomicAdd(&gout[b*64 + nt*16 + lane], ss[nt]);
                atomicAdd(&gout[NB*64 + b*64 + nt*16 + lane], sq[nt]);
            }
        }
    }
}

// MFMA pre (layers 1,2): normalize h (write back), A/Bm (f16); zero gz.
__global__ __launch_bounds__(256) void k_preM(
    float* __restrict__ h,
    const _Float16* __restrict__ pkW1, const float* __restrict__ B1,
    _Float16* __restrict__ A, _Float16* __restrict__ Bm,
    const float* __restrict__ gin, float* __restrict__ gz)
{
    alignas(16) __shared__ _Float16 sWp[8192];
    __shared__ float sMean[64], sRstd[64];
    {   // flat copy: 1024 float4
        const float4* s = (const float4*)pkW1;
        float4* d = (float4*)sWp;
        for (int i = threadIdx.x; i < 1024; i += 256) d[i] = s[i];
    }
    if (threadIdx.x < 64) {
        int b = (int)(blockIdx.x >> 5);
        float s  = gin[b*64 + threadIdx.x];
        float qq = gin[NB*64 + b*64 + threadIdx.x];
        float mean = s * (1.f/NS);
        float var  = qq * (1.f/NS) - mean*mean;
        sMean[threadIdx.x] = mean;
        sRstd[threadIdx.x] = rsqrtf(var + EPSF);
    }
    if (blockIdx.x == 0)
        for (int i = threadIdx.x; i < 2*NB*64; i += 256) gz[i] = 0.f;
    __syncthreads();
    const int lane = threadIdx.x & 63;
    const int wv = threadIdx.x >> 6;
    const int col = lane & 15, quad = lane >> 4;
    const int n0w = blockIdx.x*64 + wv*16;
    float* hp = &h[(size_t)(n0w+col)*64 + quad*8];
    float xv[16];
    *(float4*)&xv[0]  = *(const float4*)&hp[0];
    *(float4*)&xv[4]  = *(const float4*)&hp[4];
    *(float4*)&xv[8]  = *(const float4*)&hp[32];
    *(float4*)&xv[12] = *(const float4*)&hp[36];
    #pragma unroll
    for (int t2 = 0; t2 < 8; t2++) {
        int f = quad*8 + t2;
        xv[t2] = (xv[t2] - sMean[f]) * sRstd[f];
    }
    #pragma unroll
    for (int t2 = 0; t2 < 8; t2++) {
        int f = 32 + quad*8 + t2;
        xv[8+t2] = (xv[8+t2] - sMean[f]) * sRstd[f];
    }
    *(float4*)&hp[0]  = *(float4*)&xv[0];
    *(float4*)&hp[4]  = *(float4*)&xv[4];
    *(float4*)&hp[32] = *(float4*)&xv[8];
    *(float4*)&hp[36] = *(float4*)&xv[12];
    F8 af0, af1;
    af0.u[0] = pk2h(xv[0],  xv[1]);  af0.u[1] = pk2h(xv[2],  xv[3]);
    af0.u[2] = pk2h(xv[4],  xv[5]);  af0.u[3] = pk2h(xv[6],  xv[7]);
    af1.u[0] = pk2h(xv[8],  xv[9]);  af1.u[1] = pk2h(xv[10], xv[11]);
    af1.u[2] = pk2h(xv[12], xv[13]); af1.u[3] = pk2h(xv[14], xv[15]);
    float b1v[4];
    #pragma unroll
    for (int nt = 0; nt < 4; nt++) b1v[nt] = B1[nt*16+col];
    #pragma unroll
    for (int nt = 0; nt < 8; nt++) {
        f32x4 acc = {0.f,0.f,0.f,0.f};
        F8 bf; bf.v = *(const f16x8*)&sWp[(((0*8+nt)*4+quad)*16+col)*8];
        acc = __builtin_amdgcn_mfma_f32_16x16x32_f16(af0.v, bf.v, acc, 0, 0, 0);
        bf.v = *(const f16x8*)&sWp[(((1*8+nt)*4+quad)*16+col)*8];
        acc = __builtin_amdgcn_mfma_f32_16x16x32_f16(af1.v, bf.v, acc, 0, 0, 0);
        if (nt < 4) {
            float bb = b1v[nt];
            A[(size_t)(n0w + quad*4 + 0)*64 + nt*16 + col] = (_Float16)(acc.x + bb);
            A[(size_t)(n0w + quad*4 + 1)*64 + nt*16 + col] = (_Float16)(acc.y + bb);
            A[(size_t)(n0w + quad*4 + 2)*64 + nt*16 + col] = (_Float16)(acc.z + bb);
            A[(size_t)(n0w + quad*4 + 3)*64 + nt*16 + col] = (_Float16)(acc.w + bb);
        } else {
            Bm[(size_t)(n0w + quad*4 + 0)*64 + (nt-4)*16 + col] = (_Float16)acc.x;
            Bm[(size_t)(n0w + quad*4 + 1)*64 + (nt-4)*16 + col] = (_Float16)acc.y;
            Bm[(size_t)(n0w + quad*4 + 2)*64 + (nt-4)*16 + col] = (_Float16)acc.z;
            Bm[(size_t)(n0w + quad*4 + 3)*64 + (nt-4)*16 + col] = (_Float16)acc.w;
        }
    }
}

// Fused: instance-norm + decode + sigmoid + t2-term reduction
__global__ __launch_bounds__(256) void k_dec(
    const float* __restrict__ h, const float* __restrict__ Wd, const float* __restrict__ bd,
    const float* __restrict__ g, float* __restrict__ xbuf, float* __restrict__ out1,
    float* __restrict__ accum)
{
    int n = blockIdx.x*256 + threadIdx.x;
    int b = n >> 11;
    __shared__ float sM[64], sR[64];
    __shared__ float sWd[256];
    if (threadIdx.x < 64) {
        float s  = g[b*64 + threadIdx.x];
        float qq = g[NB*64 + b*64 + threadIdx.x];
        float mean = s * (1.f/NS);
        float var  = qq * (1.f/NS) - mean*mean;
        sM[threadIdx.x] = mean; sR[threadIdx.x] = rsqrtf(var + EPSF);
    }
    for (int i = threadIdx.x; i < 256; i += 256) sWd[i] = Wd[i];
    __syncthreads();
    float a0 = bd[0], a1 = bd[1], a2 = bd[2], a3 = bd[3];
    const float* hr = h + (size_t)n*64;
    #pragma unroll 8
    for (int k = 0; k < 64; k++) {
        float v = (hr[k] - sM[k]) * sR[k];
        a0 = fmaf(v, sWd[k*4+0], a0);
        a1 = fmaf(v, sWd[k*4+1], a1);
        a2 = fmaf(v, sWd[k*4+2], a2);
        a3 = fmaf(v, sWd[k*4+3], a3);
    }
    float4 o;
    o.x = 1.f/(1.f + expf(-a0));
    o.y = 1.f/(1.f + expf(-a1));
    o.z = 1.f/(1.f + expf(-a2));
    o.w = 1.f/(1.f + expf(-a3));
    *(float4*)&xbuf[(size_t)n*4] = o;
    out1[n*4+0] = o.x; out1[n*4+1] = o.y; out1[n*4+2] = o.z; out1[n*4+3] = o.w;
    float p = (1.f-o.x*o.x)*(1.f-o.y*o.y)*(1.f-o.z*o.z)*(1.f-o.w*o.w);
    for (int offs = 32; offs; offs >>= 1) p += __shfl_down(p, offs, 64);
    __shared__ float ws[4];
    if ((threadIdx.x & 63) == 0) ws[threadIdx.x >> 6] = p;
    __syncthreads();
    if (threadIdx.x == 0) atomicAdd(&accum[0], ws[0]+ws[1]+ws[2]+ws[3]);
}

// t3 pairwise term + final loss via last-block ticket
__global__ __launch_bounds__(256) void k_t3(const float* __restrict__ X,
                                            float* __restrict__ accum,
                                            float* __restrict__ out)
{
    int b = blockIdx.x >> 5, c = blockIdx.x & 31;
    __shared__ float sX[NS*4];
    const float* Xb = X + (size_t)b*NS*4;
    for (int idx = threadIdx.x; idx < NS*4; idx += 256) sX[idx] = Xb[idx];
    __syncthreads();
    const float4* sX4 = (const float4*)sX;
    int il = threadIdx.x & 63, wv = threadIdx.x >> 6;
    float4 xi = sX4[c*64 + il];
    float acc = 0.f;
    #pragma unroll 4
    for (int s = 0; s < 512; s++) {
        float4 xj = sX4[wv*512 + s];
        acc += (1.f - fmaxf(xi.x, xj.x)) * (1.f - fmaxf(xi.y, xj.y))
             * (1.f - fmaxf(xi.z, xj.z)) * (1.f - fmaxf(xi.w, xj.w));
    }
    for (int offs = 32; offs; offs >>= 1) acc += __shfl_down(acc, offs, 64);
    __shared__ float ws[4];
    if (il == 0) ws[wv] = acc;
    __syncthreads();
    if (threadIdx.x == 0) {
        atomicAdd(&accum[1], ws[0]+ws[1]+ws[2]+ws[3]);
        __threadfence();
        unsigned t = atomicAdd((unsigned int*)&accum[2], 1u);
        if (t == (unsigned)(NB*32 - 1)) {
            float A2 = __hip_atomic_load(&accum[0], __ATOMIC_ACQUIRE, __HIP_MEMORY_SCOPE_AGENT);
            float A3 = __hip_atomic_load(&accum[1], __ATOMIC_ACQUIRE, __HIP_MEMORY_SCOPE_AGENT);
            float t1 = 1.f/81.f;
            float t2 = (2.f/(NS*16.f)) * (A2 / NB);
            float t3 = (A3 / ((float)NS*(float)NS)) / NB;
            out[0] = t1 - t2 + t3;
        }
    }
}

extern "C" void kernel_launch(void* const* d_in, const int* in_sizes, int n_in,
                              void* d_out, int out_size, void* d_ws, size_t ws_size,
                              hipStream_t stream)
{
    const float* x     = (const float*)d_in[0];
    const int*   ei    = (const int*)d_in[1];
    const float* enc_w = (const float*)d_in[2];
    const float* enc_b = (const float*)d_in[3];
    const float* m1w   = (const float*)d_in[4];
    const float* m1b   = (const float*)d_in[5];
    const float* m2w   = (const float*)d_in[6];
    const float* m2b   = (const float*)d_in[7];
    const float* u1w   = (const float*)d_in[8];
    const float* u1b   = (const float*)d_in[9];
    const float* u2w   = (const float*)d_in[10];
    const float* u2b   = (const float*)d_in[11];
    const float* dw    = (const float*)d_in[12];
    const float* db    = (const float*)d_in[13];
    float* out = (float*)d_out;

    float*    h   = (float*)d_ws;              // NN*64 f32
    _Float16* Ah  = (_Float16*)(h + NN*64);    // NN*64 f16
    _Float16* Bh  = Ah + NN*64;                // NN*64 f16
    _Float16* pkM1= Bh + NN*64;                // 3*8192 f16
    _Float16* pkU1= pkM1 + 3*8192;             // 3*8192 f16
    _Float16* pkU2= pkU1 + 3*8192;             // 3*4096 f16
    _Float16* pkM2= pkU2 + 3*4096;             // 3*4096 f16
    float*    g0  = (float*)(pkM2 + 3*4096);   // 2*NB*64
    float*    g1  = g0 + 2*NB*64;              // 2*NB*64
    float*    acc = g1 + 2*NB*64;              // 4
    int*      deg = (int*)(acc + 4);           // NN
    int*      ssrc= deg + NN;                  // NN*64
    float*    xbuf= (float*)Ah;                // alias (Ah dead after last eu)

    const int* srcv = ei;
    const int* tgtv = ei + NE;
    float* gbuf[2] = {g0, g1};

    k_init<<<NN/256, 256, 0, stream>>>(deg, acc, m1w, u1w, u2w, m2w,
                                       pkM1, pkU1, pkU2, pkM2);
    k_pre0M<<<NN/64, 256, 0, stream>>>(x, enc_w, enc_b, h, pkM1, m1b,
                                       Ah, Bh, g0, srcv, tgtv, deg, ssrc);

    for (int l = 0; l < 3; l++) {
        if (l)
            k_preM<<<NN/64, 256, 0, stream>>>(h, pkM1 + l*8192, m1b + l*64,
                                              Ah, Bh,
                                              gbuf[(l+1)&1], gbuf[l&1]);
        k_eu<<<NN/16, 256, 0, stream>>>(Ah, Bh, deg, ssrc,
                                        pkM2 + l*4096, m2b + l*64,
                                        h,
                                        pkU1 + l*8192, u1b + l*64,
                                        pkU2 + l*4096, u2b + l*64,
                                        gbuf[l&1]);
    }

    k_dec<<<NN/256, 256, 0, stream>>>(h, dw, db, g0, xbuf, out + 1, acc);
    k_t3<<<NB*32, 256, 0, stream>>>(xbuf, acc, out);
}